// Round 13
// baseline (11853.527 us; speedup 1.0000x reference)
//
#include <hip/hip_runtime.h>
#include <math.h>

#define Hd 1024
#define Ed 512
#define Bv 64
#define Sv 128
#define Tv 64
#define Vv 32000
#define NB 512

typedef __attribute__((ext_vector_type(8))) short bf16x8;
typedef __attribute__((ext_vector_type(4))) float f32x4;
typedef unsigned long long ull;

__device__ __forceinline__ float sigf(float x){ return 1.0f/(1.0f + expf(-x)); }
__device__ __forceinline__ unsigned short f2bf(float f){
  unsigned u = __float_as_uint(f);
  return (unsigned short)((u + 0x7FFFu + ((u>>16)&1u)) >> 16);
}
__device__ __forceinline__ float bf2f(unsigned short b){ return __uint_as_float(((unsigned)b)<<16); }
__device__ __forceinline__ void split3(float v, unsigned short& s0, unsigned short& s1, unsigned short& s2){
  s0 = f2bf(v);
  float r1 = v - bf2f(s0);
  s1 = f2bf(r1);
  s2 = f2bf(r1 - bf2f(s1));
}
#define MF(A,B,C) __builtin_amdgcn_mfma_f32_16x16x32_bf16(A,B,C,0,0,0)

// ---- ws layout (float offsets) — fragment-ordered planes (round 12) ----
#define OFF_H    65536
#define H_PL     4259840L    // shorts per H plane (65 slots * 65536)
#define OFF_WE   6455296
#define OFF_WD   15892480
#define W_PL     6291456L    // shorts per W plane
#define OFF_WF   25329664
#define WF_PL    32768000L   // shorts per Wf plane
#define OFF_TOK  58097664
#define OFF_CNT  58105728
#define NEED_FL  58106240    // 232.4 MB

// ---------------- prep kernels (fragment-ordered planes) ----------------

__global__ __launch_bounds__(256) void k_wsplit3(
    const float* __restrict__ Wih, const float* __restrict__ Whh,
    unsigned short* __restrict__ d0, unsigned short* __restrict__ d1, unsigned short* __restrict__ d2)
{
  const int n = blockIdx.x;            // 0..4095
  const int tid = threadIdx.x;
  const int g = n >> 10, jt = (n & 1023) >> 4, nl = n & 15;
  const long base = ((long)(g*64 + jt)*48) << 9;
  #pragma unroll
  for (int i = 0; i < 6; ++i){
    int k = tid + 256*i;               // 0..1535
    float v = (k < 512) ? Wih[(long)n*512 + k] : Whh[(long)n*1024 + (k-512)];
    int kt = k >> 5, lk = (k >> 3) & 3, ke = k & 7;
    long dst = base + ((long)kt << 9) + ((lk*16 + nl) << 3) + ke;
    unsigned short s0,s1,s2; split3(v, s0,s1,s2);
    d0[dst] = s0; d1[dst] = s1; d2[dst] = s2;
  }
}

__global__ __launch_bounds__(256) void k_wfsplit(
    const float* __restrict__ W, unsigned short* __restrict__ dhi, unsigned short* __restrict__ dlo)
{
  const int v = blockIdx.x;            // 0..31999
  const int tid = threadIdx.x;
  const int vt = v >> 4, vl = v & 15;
  const long base = ((long)vt*32) << 9;
  #pragma unroll
  for (int i = 0; i < 4; ++i){
    int k = tid + 256*i;               // 0..1023
    float x = W[(long)v*1024 + k];
    int kt = k >> 5, lk = (k >> 3) & 3, ke = k & 7;
    long dst = base + ((long)kt << 9) + ((lk*16 + vl) << 3) + ke;
    unsigned short h = f2bf(x);
    dhi[dst] = h;
    dlo[dst] = f2bf(x - bf2f(h));
  }
}

// ---------------- grid barrier (relaxed poll, workgroup-only acquire) ----------------
__device__ __forceinline__ void gbar(int* cnt, int idx){
  __syncthreads();
  if (threadIdx.x == 0){
    __hip_atomic_fetch_add(&cnt[idx], 1, __ATOMIC_RELEASE, __HIP_MEMORY_SCOPE_AGENT);
    while (__hip_atomic_load(&cnt[idx], __ATOMIC_RELAXED, __HIP_MEMORY_SCOPE_AGENT) < NB)
      __builtin_amdgcn_s_sleep(2);
    __builtin_amdgcn_fence(__ATOMIC_ACQUIRE, "workgroup");
  }
  __syncthreads();
}

// ---------------- LSTM phase (fragment-ordered W and H; 256 logical blocks) ----------------
template<bool DEC>
__device__ __forceinline__ void lstm_phase(
    int lb, int tid, int slot_in, int slot_out, int tj,
    const unsigned short* __restrict__ W0s, const unsigned short* __restrict__ W1s,
    const unsigned short* __restrict__ W2s, const float* __restrict__ bias,
    const int* __restrict__ tok_src, const int* __restrict__ tf,
    const float* __restrict__ emb, const ull* __restrict__ toku,
    unsigned short* __restrict__ H, float* __restrict__ c,
    float (*g4)[16][16], short (*hst)[16][16], int* stok)
{
  const int g = tid >> 6, lane = tid & 63;
  const int l15 = lane & 15, lk = lane >> 4;
  const int jh = (lb & 63) * 16;
  const int m0 = (lb >> 6) * 16;
  const int mt = lb >> 6;
  const long wbase = ((long)(g*64 + (lb & 63))*48) << 9;
  const unsigned short* w0 = W0s + wbase;
  const unsigned short* w1 = W1s + wbase;
  const unsigned short* w2 = W2s + wbase;
  const unsigned short* h0 = H + (long)slot_in*65536;
  const unsigned short* h1 = h0 + H_PL;
  const unsigned short* h2 = h0 + 2*H_PL;

  if (tid < 16){
    int m = m0 + tid, tk;
    if (!DEC){
      tk = tok_src[m*Sv + tj];
    } else {
      if (tj == 0) tk = tok_src[m*Tv];
      else if (tf[tj] > 0) tk = tok_src[m*Tv + tj];
      else tk = (int)(~(unsigned)__hip_atomic_load(&toku[(long)(tj-1)*64 + m],
                     __ATOMIC_RELAXED, __HIP_MEMORY_SCOPE_AGENT));
    }
    stok[tid] = tk;
  }
  __syncthreads();

  f32x4 acc = (f32x4){0.f,0.f,0.f,0.f};

  // x part: K = 0..511 (W kt 0..15); emb gathered+split on the fly
  {
    const float* e0 = emb + (long)stok[l15]*Ed;
    #pragma unroll 2
    for (int kt = 0; kt < 16; ++kt){
      const int k0 = kt*32 + lk*8;
      bf16x8 b0  = *(const bf16x8*)(w0 + ((long)kt << 9) + (lane << 3));
      bf16x8 b1v = *(const bf16x8*)(w1 + ((long)kt << 9) + (lane << 3));
      bf16x8 b2  = *(const bf16x8*)(w2 + ((long)kt << 9) + (lane << 3));
      bf16x8 a0,a1,a2;
      float4 pa = *(const float4*)(e0 + k0);
      float4 pb = *(const float4*)(e0 + k0 + 4);
      float fv[8] = {pa.x,pa.y,pa.z,pa.w,pb.x,pb.y,pb.z,pb.w};
      #pragma unroll
      for (int e=0;e<8;++e){ unsigned short s0,s1,s2; split3(fv[e],s0,s1,s2);
        a0[e]=(short)s0; a1[e]=(short)s1; a2[e]=(short)s2; }
      acc = MF(a0,b0,acc); acc = MF(a1,b0,acc); acc = MF(a0,b1v,acc);
      acc = MF(a2,b0,acc); acc = MF(a0,b2,acc); acc = MF(a1,b1v,acc);
    }
  }
  // h part: K = 512..1535 (W kt 16..47; H kt 0..31, fragment-ordered)
  {
    #pragma unroll 2
    for (int kt = 0; kt < 32; ++kt){
      bf16x8 b0  = *(const bf16x8*)(w0 + ((long)(16+kt) << 9) + (lane << 3));
      bf16x8 b1v = *(const bf16x8*)(w1 + ((long)(16+kt) << 9) + (lane << 3));
      bf16x8 b2  = *(const bf16x8*)(w2 + ((long)(16+kt) << 9) + (lane << 3));
      const long ho = (((long)mt*32 + kt) << 9) + (lane << 3);
      bf16x8 a0 = *(const bf16x8*)(h0 + ho);
      bf16x8 a1 = *(const bf16x8*)(h1 + ho);
      bf16x8 a2 = *(const bf16x8*)(h2 + ho);
      acc = MF(a0,b0,acc); acc = MF(a1,b0,acc); acc = MF(a0,b1v,acc);
      acc = MF(a2,b0,acc); acc = MF(a0,b2,acc); acc = MF(a1,b1v,acc);
    }
  }

  #pragma unroll
  for (int r = 0; r < 4; ++r) g4[g][lk*4 + r][l15] = acc[r];
  __syncthreads();

  {
    const int mloc = tid >> 4, cl = tid & 15;
    const int col = jh + cl;
    float ig = g4[0][mloc][cl] + bias[col];
    float fg = g4[1][mloc][cl] + bias[Hd + col];
    float gg = g4[2][mloc][cl] + bias[2*Hd + col];
    float og = g4[3][mloc][cl] + bias[3*Hd + col];
    long idx = (long)(m0 + mloc)*Hd + col;
    float cv = c[idx];
    float cn = sigf(fg)*cv + sigf(ig)*tanhf(gg);
    float hn = sigf(og)*tanhf(cn);
    c[idx] = cn;
    unsigned short s0,s1,s2; split3(hn, s0,s1,s2);
    hst[0][mloc][cl] = (short)s0; hst[1][mloc][cl] = (short)s1; hst[2][mloc][cl] = (short)s2;
  }
  __syncthreads();
  // write-once H slot_out, fragment order: element (m=m0+r, k=jh+q*4+i)
  if (tid < 192){
    const int p = tid >> 6, t2 = tid & 63, r = t2 >> 2, q = t2 & 3;
    ull v =
        (ull)(unsigned short)hst[p][r][q*4]
      | ((ull)(unsigned short)hst[p][r][q*4+1] << 16)
      | ((ull)(unsigned short)hst[p][r][q*4+2] << 32)
      | ((ull)(unsigned short)hst[p][r][q*4+3] << 48);
    const int kt = (lb & 63) >> 1;
    const int off16 = (jh & 16) + q*4;            // 0..28
    const int lkw = off16 >> 3, keb = off16 & 7;  // keb in {0,4}
    ull* dst = (ull*)(H + (long)p*H_PL + (long)slot_out*65536
                      + (((long)mt*32 + kt) << 9) + ((lkw*16 + r) << 3) + keb);
    __hip_atomic_store(dst, v, __ATOMIC_RELAXED, __HIP_MEMORY_SCOPE_AGENT);
  }
}

// ---------------- argmax-only FC phase: 500 blocks x 64 vocab, fragment-ordered ----------------
// Per-accumulator MFMA sequence identical to round 12: per kt, (ah,bh),(al,bh),(ah,bl).
__device__ __forceinline__ void fc_phase(
    int b, int tid,
    const unsigned short* __restrict__ hhi, const unsigned short* __restrict__ hlo,
    const unsigned short* __restrict__ Wfhi, const unsigned short* __restrict__ Wflo,
    const float* __restrict__ bfc,
    ull* __restrict__ tslot, ull* amax)
{
  if (tid < 64) amax[tid] = 0ULL;
  __syncthreads();
  const int wv = tid >> 6, lane = tid & 63;
  const int l15 = lane & 15, lk = lane >> 4;
  const int vt = b*4 + wv;               // 0..1999
  const int v0 = vt*16 + l15;

  f32x4 acc[4];
  #pragma unroll
  for (int mt=0; mt<4; ++mt) acc[mt] = (f32x4){0.f,0.f,0.f,0.f};

  #pragma unroll 2
  for (int kt = 0; kt < 32; ++kt){
    const long wo = (((long)vt*32 + kt) << 9) + (lane << 3);
    bf16x8 bh = *(const bf16x8*)(Wfhi + wo);
    bf16x8 bl = *(const bf16x8*)(Wflo + wo);
    #pragma unroll
    for (int mt=0; mt<4; ++mt){
      const long ho = (((long)mt*32 + kt) << 9) + (lane << 3);
      bf16x8 ah = *(const bf16x8*)(hhi + ho);
      bf16x8 al = *(const bf16x8*)(hlo + ho);
      acc[mt] = MF(ah, bh, acc[mt]);
      acc[mt] = MF(al, bh, acc[mt]);
      acc[mt] = MF(ah, bl, acc[mt]);
    }
  }
  float bb0 = bfc[v0];
  #pragma unroll
  for (int mt=0; mt<4; ++mt){
    #pragma unroll
    for (int r=0; r<4; ++r){
      int m = mt*16 + lk*4 + r;
      float f0 = acc[mt][r] + bb0;
      unsigned u0 = __float_as_uint(f0); u0 ^= (u0 >> 31) ? 0xFFFFFFFFu : 0x80000000u;
      ull cm = ((ull)u0 << 32) | (unsigned)(~v0);
      #pragma unroll
      for (int d=1; d<16; d<<=1){
        ull o = __shfl_xor(cm, d);
        if (o > cm) cm = o;
      }
      if (l15 == 0) atomicMax(&amax[m], cm);
    }
  }
  __syncthreads();
  if (tid < 64) atomicMax(tslot + tid, amax[tid]);
}

// ---------------- the mega kernel: 512 blocks, 2 per CU ----------------
__global__ __launch_bounds__(256, 2) void k_mega(
    const int* __restrict__ src, const int* __restrict__ trg, const int* __restrict__ tf,
    const float* __restrict__ enc_emb, const float* __restrict__ dec_emb,
    const float* __restrict__ b_e, const float* __restrict__ b_d,
    const float* __restrict__ bfc,
    float* __restrict__ ws)
{
  __shared__ float g4[4][16][16];
  __shared__ short hst[3][16][16];
  __shared__ int stok[16];
  __shared__ ull amax[64];

  const int b = blockIdx.x, tid = threadIdx.x;
  // LSTM role: chosen so each CU gets exactly one LSTM-active block under either
  // consecutive-pair or stride-256 block->CU placement.
  const bool rl = ((b ^ (b >> 8)) & 1) == 0;
  const int lb = (b < 256) ? (b >> 1) : (128 + ((b - 256) >> 1));

  float* c = ws;
  unsigned short* H = (unsigned short*)(ws + OFF_H);
  const unsigned short* We0 = (const unsigned short*)(ws + OFF_WE);
  const unsigned short* We1 = We0 + W_PL;
  const unsigned short* We2 = We0 + 2*W_PL;
  const unsigned short* Wd0 = (const unsigned short*)(ws + OFF_WD);
  const unsigned short* Wd1 = Wd0 + W_PL;
  const unsigned short* Wd2 = Wd0 + 2*W_PL;
  const unsigned short* Wfhi = (const unsigned short*)(ws + OFF_WF);
  const unsigned short* Wflo = Wfhi + WF_PL;
  ull* toku = (ull*)(ws + OFF_TOK);
  int* cnt = (int*)(ws + OFF_CNT);
  int bar = 0;

  // init: LSTM-role blocks zero own c tile + stripe of H slot 64 (3 planes x 8192 ULL = 256 x 96)
  if (rl){
    const int jh = (lb & 63)*16, m0 = (lb >> 6)*16;
    const int mloc = tid >> 4, cl = tid & 15;
    c[(long)(m0+mloc)*Hd + jh + cl] = 0.f;
    if (tid < 96){
      long off_ull = (long)lb*96 + tid;      // 0 .. 24575
      int p = (int)(off_ull >> 13);          // plane 0..2
      long q = off_ull & 8191;
      ull* dst = (ull*)(H + (long)p*H_PL + 64L*65536) + q;
      __hip_atomic_store(dst, 0ULL, __ATOMIC_RELAXED, __HIP_MEMORY_SCOPE_AGENT);
    }
  }
  gbar(cnt, bar++);

  // encoder: slot_in = 63 + ((t+1)&1), slot_out = 63 + (t&1); t=0 reads zeroed slot 64
  for (int t = 0; t < Sv; ++t){
    if (rl)
      lstm_phase<false>(lb, tid, 63 + ((t+1)&1), 63 + (t&1), t,
          We0, We1, We2, b_e, src, (const int*)0, enc_emb,
          (const ull*)0, H, c, g4, hst, stok);
    gbar(cnt, bar++);
  }
  // decoder: step j reads slot (j==0 ? 64 : j-1), writes slot j
  for (int j = 0; j < Tv-1; ++j){
    if (rl)
      lstm_phase<true>(lb, tid, (j == 0) ? 64 : (j-1), j, j,
          Wd0, Wd1, Wd2, b_d, trg, tf, dec_emb, toku, H, c, g4, hst, stok);
    gbar(cnt, bar++);
    if (j < Tv-2 && tf[j+1] == 0){
      if (b < 500){
        const unsigned short* h0 = H + (long)j*65536;
        fc_phase(b, tid, h0, h0 + H_PL, Wfhi, Wflo, bfc, toku + (long)j*64, amax);
      }
      gbar(cnt, bar++);
    }
  }
}

// ---------------- batched logits: 4 j per block, grid (500,16), fragment-ordered ----------------
__global__ __launch_bounds__(256) void k_fcall(
    const unsigned short* __restrict__ Wfhi, const unsigned short* __restrict__ Wflo,
    const float* __restrict__ bfc,
    const unsigned short* __restrict__ H, float* __restrict__ out)
{
  const int tid = threadIdx.x;
  const int wv = tid >> 6, lane = tid & 63;
  const int l15 = lane & 15, lk = lane >> 4;
  const int vt = blockIdx.x*4 + wv;
  const int vcol = vt*16 + l15;
  const int jbase = blockIdx.y*4;
  const unsigned short* h0b = H + (long)jbase*65536;
  const unsigned short* h1b = h0b + H_PL;

  f32x4 acc[4][4];
  #pragma unroll
  for (int jj=0;jj<4;++jj)
    #pragma unroll
    for (int mt=0;mt<4;++mt) acc[jj][mt] = (f32x4){0.f,0.f,0.f,0.f};

  for (int kt = 0; kt < 32; ++kt){
    const long wo = (((long)vt*32 + kt) << 9) + (lane << 3);
    bf16x8 bh = *(const bf16x8*)(Wfhi + wo);
    bf16x8 bl = *(const bf16x8*)(Wflo + wo);
    #pragma unroll
    for (int jj=0;jj<4;++jj){
      if (jbase + jj <= 62){
        #pragma unroll
        for (int mt=0;mt<4;++mt){
          const long ho = (long)jj*65536 + (((long)mt*32 + kt) << 9) + (lane << 3);
          bf16x8 ah = *(const bf16x8*)(h0b + ho);
          bf16x8 al = *(const bf16x8*)(h1b + ho);
          acc[jj][mt] = MF(ah, bh, acc[jj][mt]);
          acc[jj][mt] = MF(al, bh, acc[jj][mt]);
          acc[jj][mt] = MF(ah, bl, acc[jj][mt]);
        }
      }
    }
  }
  float bb = bfc[vcol];
  #pragma unroll
  for (int jj=0;jj<4;++jj){
    if (jbase + jj <= 62){
      #pragma unroll
      for (int mt=0;mt<4;++mt){
        #pragma unroll
        for (int r=0;r<4;++r){
          int m = mt*16 + lk*4 + r;
          out[((long)m*Tv + (jbase+jj+1))*(long)Vv + vcol] = acc[jj][mt][r] + bb;
        }
      }
    }
  }
  if (blockIdx.y == 0){
    const int vb = blockIdx.x*64;
    for (int i = tid; i < 4096; i += 256){
      int m = i >> 6, v = vb + (i & 63);
      out[(long)m*Tv*(long)Vv + v] = 0.f;
    }
  }
}

// ---------------- fallback (round-2 proven path, used only if ws too small) ----------------

__global__ __launch_bounds__(256) void k_initC(float* __restrict__ ws, float* __restrict__ out){
  long i = (long)blockIdx.x*256 + threadIdx.x;
  if (i < 262144){ ws[i] = 0.f; }
  else {
    long r = i - 262144;
    long m = r / Vv, v = r % Vv;
    out[m*Tv*(long)Vv + v] = 0.f;
  }
}

__global__ __launch_bounds__(256) void k_stepC(
    int mode, int t,
    const int* __restrict__ tok_src, const int* __restrict__ tf_mask,
    const int* __restrict__ token_buf, const float* __restrict__ emb,
    const float* __restrict__ Wih, const float* __restrict__ Whh,
    const float* __restrict__ bias,
    const float* __restrict__ h_in, const float* __restrict__ c_in,
    float* __restrict__ h_out, float* __restrict__ c_out,
    unsigned short* __restrict__ hsp_hi, unsigned short* __restrict__ hsp_lo)
{
  __shared__ __align__(16) float tile[8*1536];
  __shared__ float gbuf[4*8*32];
  __shared__ int toks[8];
  const int tid = threadIdx.x;
  const int m0 = blockIdx.y*8, jh0 = blockIdx.x*32;
  if (tid < 8){
    int m = m0 + tid; int tok;
    if (mode == 0) tok = tok_src[m*Sv + t];
    else { if (t == 0) tok = tok_src[m*Tv];
           else tok = (tf_mask[t] > 0) ? tok_src[m*Tv + t] : token_buf[m]; }
    toks[tid] = tok;
  }
  __syncthreads();
  { float4* t4 = (float4*)tile;
    #pragma unroll
    for (int r = 0; r < 12; ++r){
      int f = tid + 256*r; int row = f / 384, o = f % 384; float4 v;
      if (o < 128) v = ((const float4*)(emb + (long)toks[row]*Ed))[o];
      else         v = ((const float4*)(h_in + (long)(m0+row)*Hd))[o-128];
      t4[row*384 + o] = v; } }
  __syncthreads();
  const int g = tid >> 6, sx = tid & 63, jl = sx & 31, mg = sx >> 5;
  const int col = g*Hd + jh0 + jl;
  const float4* wx = (const float4*)(Wih + (long)col*Ed);
  const float4* wh = (const float4*)(Whh + (long)col*Hd);
  const float4* t4 = (const float4*)tile;
  const int mb = mg*4;
  float bq = bias[col];
  float a0=bq, a1=bq, a2=bq, a3=bq;
  for (int k = 0; k < 128; ++k){
    float4 w = wx[k];
    float4 v0 = t4[(mb+0)*384 + k]; float4 v1 = t4[(mb+1)*384 + k];
    float4 v2 = t4[(mb+2)*384 + k]; float4 v3 = t4[(mb+3)*384 + k];
    a0 += w.x*v0.x + w.y*v0.y + w.z*v0.z + w.w*v0.w;
    a1 += w.x*v1.x + w.y*v1.y + w.z*v1.z + w.w*v1.w;
    a2 += w.x*v2.x + w.y*v2.y + w.z*v2.z + w.w*v2.w;
    a3 += w.x*v3.x + w.y*v3.y + w.z*v3.z + w.w*v3.w;
  }
  for (int k = 0; k < 256; ++k){
    float4 w = wh[k];
    float4 v0 = t4[(mb+0)*384 + 128 + k]; float4 v1 = t4[(mb+1)*384 + 128 + k];
    float4 v2 = t4[(mb+2)*384 + 128 + k]; float4 v3 = t4[(mb+3)*384 + 128 + k];
    a0 += w.x*v0.x + w.y*v0.y + w.z*v0.z + w.w*v0.w;
    a1 += w.x*v1.x + w.y*v1.y + w.z*v1.z + w.w*v1.w;
    a2 += w.x*v2.x + w.y*v2.y + w.z*v2.z + w.w*v2.w;
    a3 += w.x*v3.x + w.y*v3.y + w.z*v3.z + w.w*v3.w;
  }
  gbuf[g*256 + (mb+0)*32 + jl] = a0; gbuf[g*256 + (mb+1)*32 + jl] = a1;
  gbuf[g*256 + (mb+2)*32 + jl] = a2; gbuf[g*256 + (mb+3)*32 + jl] = a3;
  __syncthreads();
  const int ml = tid >> 5, j2 = tid & 31;
  float ig = gbuf[0*256 + ml*32 + j2];
  float fg = gbuf[1*256 + ml*32 + j2];
  float gg = gbuf[2*256 + ml*32 + j2];
  float og = gbuf[3*256 + ml*32 + j2];
  long idx = (long)(m0+ml)*Hd + jh0 + j2;
  float cc = c_in[idx];
  float cn = sigf(fg)*cc + sigf(ig)*tanhf(gg);
  float hn = sigf(og)*tanhf(cn);
  c_out[idx] = cn; h_out[idx] = hn;
  unsigned short hh = f2bf(hn);
  hsp_hi[idx] = hh; hsp_lo[idx] = f2bf(hn - bf2f(hh));
}

__global__ __launch_bounds__(256) void k_fcC(
    int j, const unsigned short* __restrict__ hhi, const unsigned short* __restrict__ hlo,
    const float* __restrict__ Wfc, const float* __restrict__ bfc, float* __restrict__ out)
{
  const int tid = threadIdx.x;
  const int wv = tid >> 6, lane = tid & 63;
  const int l15 = lane & 15, lk = lane >> 4;
  const int vcol = blockIdx.x*64 + wv*16 + l15;
  const float* wrow = Wfc + (long)vcol*Hd;
  f32x4 acc[4];
  #pragma unroll
  for (int mt=0; mt<4; ++mt) acc[mt] = (f32x4){0.f,0.f,0.f,0.f};
  #pragma unroll 2
  for (int kt = 0; kt < 32; ++kt){
    const int k0 = kt*32 + lk*8;
    float4 wa = *(const float4*)(wrow + k0);
    float4 wb = *(const float4*)(wrow + k0 + 4);
    float wf[8] = {wa.x,wa.y,wa.z,wa.w,wb.x,wb.y,wb.z,wb.w};
    bf16x8 bh, bl;
    #pragma unroll
    for (int e=0;e<8;++e){
      unsigned short h = f2bf(wf[e]);
      bh[e] = (short)h; bl[e] = (short)f2bf(wf[e] - bf2f(h));
    }
    #pragma unroll
    for (int mt=0; mt<4; ++mt){
      const int row = mt*16 + l15;
      bf16x8 ah = *(const bf16x8*)(hhi + row*Hd + k0);
      bf16x8 al = *(const bf16x8*)(hlo + row*Hd + k0);
      acc[mt] = MF(ah, bh, acc[mt]);
      acc[mt] = MF(al, bh, acc[mt]);
      acc[mt] = MF(ah, bl, acc[mt]);
    }
  }
  float bb = bfc[vcol];
  #pragma unroll
  for (int mt=0; mt<4; ++mt)
    #pragma unroll
    for (int r=0; r<4; ++r){
      int m = mt*16 + lk*4 + r;
      out[((long)m*Tv + (j+1))*(long)Vv + vcol] = acc[mt][r] + bb;
    }
}

__global__ __launch_bounds__(256) void k_argmaxC(
    int j, const float* __restrict__ out, int* __restrict__ token_buf)
{
  __shared__ float sval[256];
  __shared__ int   sidx[256];
  const int m = blockIdx.x, tid = threadIdx.x;
  const float* base = out + ((long)m*Tv + (j+1))*(long)Vv;
  float best = -INFINITY; int bi = 0;
  for (int v = tid; v < Vv; v += 256){
    float f = base[v];
    if (f > best){ best = f; bi = v; }
  }
  sval[tid] = best; sidx[tid] = bi;
  __syncthreads();
  for (int s2 = 128; s2 > 0; s2 >>= 1){
    if (tid < s2){
      float ov = sval[tid+s2]; int oi = sidx[tid+s2];
      if (ov > sval[tid] || (ov == sval[tid] && oi < sidx[tid])){
        sval[tid] = ov; sidx[tid] = oi;
      }
    }
    __syncthreads();
  }
  if (tid == 0) token_buf[m] = sidx[0];
}

extern "C" void kernel_launch(void* const* d_in, const int* in_sizes, int n_in,
                              void* d_out, int out_size, void* d_ws, size_t ws_size,
                              hipStream_t stream)
{
  const int*   src     = (const int*)  d_in[0];
  const int*   trg     = (const int*)  d_in[1];
  const int*   tf      = (const int*)  d_in[2];
  const float* enc_emb = (const float*)d_in[3];
  const float* dec_emb = (const float*)d_in[4];
  const float* Wih_e   = (const float*)d_in[5];
  const float* Whh_e   = (const float*)d_in[6];
  const float* b_e     = (const float*)d_in[7];
  const float* Wih_d   = (const float*)d_in[8];
  const float* Whh_d   = (const float*)d_in[9];
  const float* b_d     = (const float*)d_in[10];
  const float* Wfc     = (const float*)d_in[11];
  const float* bfc     = (const float*)d_in[12];
  float* out = (float*)d_out;
  float* ws  = (float*)d_ws;

  if (ws_size >= (size_t)NEED_FL * 4ULL){
    unsigned short* We0 = (unsigned short*)(ws + OFF_WE);
    unsigned short* Wd0 = (unsigned short*)(ws + OFF_WD);
    unsigned short* Wf0 = (unsigned short*)(ws + OFF_WF);
    unsigned short* Hb  = (unsigned short*)(ws + OFF_H);

    hipMemsetAsync((void*)(ws + OFF_TOK), 0, (size_t)(NEED_FL - OFF_TOK) * 4ULL, stream);
    k_wsplit3<<<4096, 256, 0, stream>>>(Wih_e, Whh_e, We0, We0 + W_PL, We0 + 2*W_PL);
    k_wsplit3<<<4096, 256, 0, stream>>>(Wih_d, Whh_d, Wd0, Wd0 + W_PL, Wd0 + 2*W_PL);
    k_wfsplit<<<32000, 256, 0, stream>>>(Wfc, Wf0, Wf0 + WF_PL);
    k_mega<<<NB, 256, 0, stream>>>(src, trg, tf, enc_emb, dec_emb, b_e, b_d, bfc, ws);
    k_fcall<<<dim3(500, 16), 256, 0, stream>>>(Wf0, Wf0 + WF_PL, bfc, Hb, out);
  } else {
    // fallback: round-2 proven multi-kernel path
    float* hbuf[2] = { ws,            ws + 65536 };
    float* cbuf[2] = { ws + 131072,   ws + 196608 };
    int*   tokbuf  = (int*)(ws + 262144);
    unsigned short* hsp_hi = (unsigned short*)(ws + 262208);
    unsigned short* hsp_lo = (unsigned short*)(ws + 262208 + 32768);

    k_initC<<<9024, 256, 0, stream>>>(ws, out);
    int cur = 0;
    for (int t = 0; t < Sv; ++t){
      k_stepC<<<dim3(32,8), 256, 0, stream>>>(0, t, src, tf, tokbuf, enc_emb,
          Wih_e, Whh_e, b_e, hbuf[cur], cbuf[cur], hbuf[cur^1], cbuf[cur^1], hsp_hi, hsp_lo);
      cur ^= 1;
    }
    for (int j = 0; j < Tv-1; ++j){
      k_stepC<<<dim3(32,8), 256, 0, stream>>>(1, j, trg, tf, tokbuf, dec_emb,
          Wih_d, Whh_d, b_d, hbuf[cur], cbuf[cur], hbuf[cur^1], cbuf[cur^1], hsp_hi, hsp_lo);
      cur ^= 1;
      k_fcC<<<500, 256, 0, stream>>>(j, hsp_hi, hsp_lo, Wfc, bfc, out);
      if (j < Tv-2) k_argmaxC<<<64, 256, 0, stream>>>(j, out, tokbuf);
    }
  }
}

// Round 14
// 11648.449 us; speedup vs baseline: 1.0176x; 1.0176x over previous
//
#include <hip/hip_runtime.h>
#include <math.h>

#define Hd 1024
#define Ed 512
#define Bv 64
#define Sv 128
#define Tv 64
#define Vv 32000
#define NB 512

typedef __attribute__((ext_vector_type(8))) short bf16x8;
typedef __attribute__((ext_vector_type(4))) float f32x4;
typedef unsigned long long ull;

__device__ __forceinline__ float sigf(float x){ return 1.0f/(1.0f + expf(-x)); }
__device__ __forceinline__ unsigned short f2bf(float f){
  unsigned u = __float_as_uint(f);
  return (unsigned short)((u + 0x7FFFu + ((u>>16)&1u)) >> 16);
}
__device__ __forceinline__ float bf2f(unsigned short b){ return __uint_as_float(((unsigned)b)<<16); }
__device__ __forceinline__ void split3(float v, unsigned short& s0, unsigned short& s1, unsigned short& s2){
  s0 = f2bf(v);
  float r1 = v - bf2f(s0);
  s1 = f2bf(r1);
  s2 = f2bf(r1 - bf2f(s1));
}
#define MF(A,B,C) __builtin_amdgcn_mfma_f32_16x16x32_bf16(A,B,C,0,0,0)

// ---- ws layout (float offsets) — fragment-ordered planes (round 12) ----
#define OFF_H    65536
#define H_PL     4259840L    // shorts per H plane (65 slots * 65536)
#define OFF_WE   6455296
#define OFF_WD   15892480
#define W_PL     6291456L    // shorts per W plane
#define OFF_WF   25329664
#define WF_PL    32768000L   // shorts per Wf plane
#define OFF_TOK  58097664
#define OFF_CNT  58105728
#define NEED_FL  58106240    // 232.4 MB

// ---------------- prep kernels (fragment-ordered planes) ----------------

__global__ __launch_bounds__(256) void k_wsplit3(
    const float* __restrict__ Wih, const float* __restrict__ Whh,
    unsigned short* __restrict__ d0, unsigned short* __restrict__ d1, unsigned short* __restrict__ d2)
{
  const int n = blockIdx.x;            // 0..4095
  const int tid = threadIdx.x;
  const int g = n >> 10, jt = (n & 1023) >> 4, nl = n & 15;
  const long base = ((long)(g*64 + jt)*48) << 9;
  #pragma unroll
  for (int i = 0; i < 6; ++i){
    int k = tid + 256*i;               // 0..1535
    float v = (k < 512) ? Wih[(long)n*512 + k] : Whh[(long)n*1024 + (k-512)];
    int kt = k >> 5, lk = (k >> 3) & 3, ke = k & 7;
    long dst = base + ((long)kt << 9) + ((lk*16 + nl) << 3) + ke;
    unsigned short s0,s1,s2; split3(v, s0,s1,s2);
    d0[dst] = s0; d1[dst] = s1; d2[dst] = s2;
  }
}

__global__ __launch_bounds__(256) void k_wfsplit(
    const float* __restrict__ W, unsigned short* __restrict__ dhi, unsigned short* __restrict__ dlo)
{
  const int v = blockIdx.x;            // 0..31999
  const int tid = threadIdx.x;
  const int vt = v >> 4, vl = v & 15;
  const long base = ((long)vt*32) << 9;
  #pragma unroll
  for (int i = 0; i < 4; ++i){
    int k = tid + 256*i;               // 0..1023
    float x = W[(long)v*1024 + k];
    int kt = k >> 5, lk = (k >> 3) & 3, ke = k & 7;
    long dst = base + ((long)kt << 9) + ((lk*16 + vl) << 3) + ke;
    unsigned short h = f2bf(x);
    dhi[dst] = h;
    dlo[dst] = f2bf(x - bf2f(h));
  }
}

// ---------------- grid barrier (relaxed poll, workgroup-only acquire) ----------------
__device__ __forceinline__ void gbar(int* cnt, int idx){
  __syncthreads();
  if (threadIdx.x == 0){
    __hip_atomic_fetch_add(&cnt[idx], 1, __ATOMIC_RELEASE, __HIP_MEMORY_SCOPE_AGENT);
    while (__hip_atomic_load(&cnt[idx], __ATOMIC_RELAXED, __HIP_MEMORY_SCOPE_AGENT) < NB)
      __builtin_amdgcn_s_sleep(2);
    __builtin_amdgcn_fence(__ATOMIC_ACQUIRE, "workgroup");
  }
  __syncthreads();
}

// ---------------- LSTM phase (fragment-ordered W and H; 256 logical blocks) ----------------
template<bool DEC>
__device__ __forceinline__ void lstm_phase(
    int lb, int tid, int slot_in, int slot_out, int tj,
    const unsigned short* __restrict__ W0s, const unsigned short* __restrict__ W1s,
    const unsigned short* __restrict__ W2s, const float* __restrict__ bias,
    const int* __restrict__ tok_src, const int* __restrict__ tf,
    const float* __restrict__ emb, const ull* __restrict__ toku,
    unsigned short* __restrict__ H, float* __restrict__ c,
    float (*g4)[16][16], short (*hst)[16][16], int* stok)
{
  const int g = tid >> 6, lane = tid & 63;
  const int l15 = lane & 15, lk = lane >> 4;
  const int jh = (lb & 63) * 16;
  const int m0 = (lb >> 6) * 16;
  const int mt = lb >> 6;
  const long wbase = ((long)(g*64 + (lb & 63))*48) << 9;
  const unsigned short* w0 = W0s + wbase;
  const unsigned short* w1 = W1s + wbase;
  const unsigned short* w2 = W2s + wbase;
  const unsigned short* h0 = H + (long)slot_in*65536;
  const unsigned short* h1 = h0 + H_PL;
  const unsigned short* h2 = h0 + 2*H_PL;

  if (tid < 16){
    int m = m0 + tid, tk;
    if (!DEC){
      tk = tok_src[m*Sv + tj];
    } else {
      if (tj == 0) tk = tok_src[m*Tv];
      else if (tf[tj] > 0) tk = tok_src[m*Tv + tj];
      else tk = (int)(~(unsigned)__hip_atomic_load(&toku[(long)(tj-1)*64 + m],
                     __ATOMIC_RELAXED, __HIP_MEMORY_SCOPE_AGENT));
    }
    stok[tid] = tk;
  }
  __syncthreads();

  f32x4 acc = (f32x4){0.f,0.f,0.f,0.f};

  // x part: K = 0..511 (W kt 0..15); emb gathered+split on the fly
  {
    const float* e0 = emb + (long)stok[l15]*Ed;
    #pragma unroll 2
    for (int kt = 0; kt < 16; ++kt){
      const int k0 = kt*32 + lk*8;
      bf16x8 b0  = *(const bf16x8*)(w0 + ((long)kt << 9) + (lane << 3));
      bf16x8 b1v = *(const bf16x8*)(w1 + ((long)kt << 9) + (lane << 3));
      bf16x8 b2  = *(const bf16x8*)(w2 + ((long)kt << 9) + (lane << 3));
      bf16x8 a0,a1,a2;
      float4 pa = *(const float4*)(e0 + k0);
      float4 pb = *(const float4*)(e0 + k0 + 4);
      float fv[8] = {pa.x,pa.y,pa.z,pa.w,pb.x,pb.y,pb.z,pb.w};
      #pragma unroll
      for (int e=0;e<8;++e){ unsigned short s0,s1,s2; split3(fv[e],s0,s1,s2);
        a0[e]=(short)s0; a1[e]=(short)s1; a2[e]=(short)s2; }
      acc = MF(a0,b0,acc); acc = MF(a1,b0,acc); acc = MF(a0,b1v,acc);
      acc = MF(a2,b0,acc); acc = MF(a0,b2,acc); acc = MF(a1,b1v,acc);
    }
  }
  // h part: K = 512..1535 (W kt 16..47; H kt 0..31, fragment-ordered)
  {
    #pragma unroll 2
    for (int kt = 0; kt < 32; ++kt){
      bf16x8 b0  = *(const bf16x8*)(w0 + ((long)(16+kt) << 9) + (lane << 3));
      bf16x8 b1v = *(const bf16x8*)(w1 + ((long)(16+kt) << 9) + (lane << 3));
      bf16x8 b2  = *(const bf16x8*)(w2 + ((long)(16+kt) << 9) + (lane << 3));
      const long ho = (((long)mt*32 + kt) << 9) + (lane << 3);
      bf16x8 a0 = *(const bf16x8*)(h0 + ho);
      bf16x8 a1 = *(const bf16x8*)(h1 + ho);
      bf16x8 a2 = *(const bf16x8*)(h2 + ho);
      acc = MF(a0,b0,acc); acc = MF(a1,b0,acc); acc = MF(a0,b1v,acc);
      acc = MF(a2,b0,acc); acc = MF(a0,b2,acc); acc = MF(a1,b1v,acc);
    }
  }

  #pragma unroll
  for (int r = 0; r < 4; ++r) g4[g][lk*4 + r][l15] = acc[r];
  __syncthreads();

  {
    const int mloc = tid >> 4, cl = tid & 15;
    const int col = jh + cl;
    float ig = g4[0][mloc][cl] + bias[col];
    float fg = g4[1][mloc][cl] + bias[Hd + col];
    float gg = g4[2][mloc][cl] + bias[2*Hd + col];
    float og = g4[3][mloc][cl] + bias[3*Hd + col];
    long idx = (long)(m0 + mloc)*Hd + col;
    float cv = c[idx];
    float cn = sigf(fg)*cv + sigf(ig)*tanhf(gg);
    float hn = sigf(og)*tanhf(cn);
    c[idx] = cn;
    unsigned short s0,s1,s2; split3(hn, s0,s1,s2);
    hst[0][mloc][cl] = (short)s0; hst[1][mloc][cl] = (short)s1; hst[2][mloc][cl] = (short)s2;
  }
  __syncthreads();
  // write-once H slot_out, fragment order: element (m=m0+r, k=jh+q*4+i)
  if (tid < 192){
    const int p = tid >> 6, t2 = tid & 63, r = t2 >> 2, q = t2 & 3;
    ull v =
        (ull)(unsigned short)hst[p][r][q*4]
      | ((ull)(unsigned short)hst[p][r][q*4+1] << 16)
      | ((ull)(unsigned short)hst[p][r][q*4+2] << 32)
      | ((ull)(unsigned short)hst[p][r][q*4+3] << 48);
    const int kt = (lb & 63) >> 1;
    const int off16 = (jh & 16) + q*4;            // 0..28
    const int lkw = off16 >> 3, keb = off16 & 7;  // keb in {0,4}
    ull* dst = (ull*)(H + (long)p*H_PL + (long)slot_out*65536
                      + (((long)mt*32 + kt) << 9) + ((lkw*16 + r) << 3) + keb);
    __hip_atomic_store(dst, v, __ATOMIC_RELAXED, __HIP_MEMORY_SCOPE_AGENT);
  }
}

// ---------------- argmax-only FC phase: 500 blocks x 64 vocab, fragment-ordered ----------------
__device__ __forceinline__ void fc_phase(
    int b, int tid,
    const unsigned short* __restrict__ hhi, const unsigned short* __restrict__ hlo,
    const unsigned short* __restrict__ Wfhi, const unsigned short* __restrict__ Wflo,
    const float* __restrict__ bfc,
    ull* __restrict__ tslot, ull* amax)
{
  if (tid < 64) amax[tid] = 0ULL;
  __syncthreads();
  const int wv = tid >> 6, lane = tid & 63;
  const int l15 = lane & 15, lk = lane >> 4;
  const int vt = b*4 + wv;               // 0..1999
  const int v0 = vt*16 + l15;

  f32x4 acc[4];
  #pragma unroll
  for (int mt=0; mt<4; ++mt) acc[mt] = (f32x4){0.f,0.f,0.f,0.f};

  #pragma unroll 2
  for (int kt = 0; kt < 32; ++kt){
    const long wo = (((long)vt*32 + kt) << 9) + (lane << 3);
    bf16x8 bh = *(const bf16x8*)(Wfhi + wo);
    bf16x8 bl = *(const bf16x8*)(Wflo + wo);
    #pragma unroll
    for (int mt=0; mt<4; ++mt){
      const long ho = (((long)mt*32 + kt) << 9) + (lane << 3);
      bf16x8 ah = *(const bf16x8*)(hhi + ho);
      bf16x8 al = *(const bf16x8*)(hlo + ho);
      acc[mt] = MF(ah, bh, acc[mt]);
      acc[mt] = MF(al, bh, acc[mt]);
      acc[mt] = MF(ah, bl, acc[mt]);
    }
  }
  float bb0 = bfc[v0];
  #pragma unroll
  for (int mt=0; mt<4; ++mt){
    #pragma unroll
    for (int r=0; r<4; ++r){
      int m = mt*16 + lk*4 + r;
      float f0 = acc[mt][r] + bb0;
      unsigned u0 = __float_as_uint(f0); u0 ^= (u0 >> 31) ? 0xFFFFFFFFu : 0x80000000u;
      ull cm = ((ull)u0 << 32) | (unsigned)(~v0);
      #pragma unroll
      for (int d=1; d<16; d<<=1){
        ull o = __shfl_xor(cm, d);
        if (o > cm) cm = o;
      }
      if (l15 == 0) atomicMax(&amax[m], cm);
    }
  }
  __syncthreads();
  if (tid < 64) atomicMax(tslot + tid, amax[tid]);
}

// ---------------- the mega kernel: 512 blocks, 2 per CU; LSTM role = b<256 (r12 placement) ----------------
__global__ __launch_bounds__(256, 2) void k_mega(
    const int* __restrict__ src, const int* __restrict__ trg, const int* __restrict__ tf,
    const float* __restrict__ enc_emb, const float* __restrict__ dec_emb,
    const float* __restrict__ b_e, const float* __restrict__ b_d,
    const float* __restrict__ bfc,
    float* __restrict__ ws)
{
  __shared__ float g4[4][16][16];
  __shared__ short hst[3][16][16];
  __shared__ int stok[16];
  __shared__ ull amax[64];

  const int b = blockIdx.x, tid = threadIdx.x;
  // LSTM role: blocks 0..255 with lb=b — identical XCD/jh-tile placement to round 12
  // (XCD = b%8 round-robin -> 8 jh-tiles per XCD -> W slice ~4.7MB ~ L2).
  const bool rl = (b < 256);
  const int lb = b;

  float* c = ws;
  unsigned short* H = (unsigned short*)(ws + OFF_H);
  const unsigned short* We0 = (const unsigned short*)(ws + OFF_WE);
  const unsigned short* We1 = We0 + W_PL;
  const unsigned short* We2 = We0 + 2*W_PL;
  const unsigned short* Wd0 = (const unsigned short*)(ws + OFF_WD);
  const unsigned short* Wd1 = Wd0 + W_PL;
  const unsigned short* Wd2 = Wd0 + 2*W_PL;
  const unsigned short* Wfhi = (const unsigned short*)(ws + OFF_WF);
  const unsigned short* Wflo = Wfhi + WF_PL;
  ull* toku = (ull*)(ws + OFF_TOK);
  int* cnt = (int*)(ws + OFF_CNT);
  int bar = 0;

  // init: LSTM-role blocks zero own c tile + stripe of H slot 64 (3 planes x 8192 ULL = 256 x 96)
  if (rl){
    const int jh = (lb & 63)*16, m0 = (lb >> 6)*16;
    const int mloc = tid >> 4, cl = tid & 15;
    c[(long)(m0+mloc)*Hd + jh + cl] = 0.f;
    if (tid < 96){
      long off_ull = (long)lb*96 + tid;      // 0 .. 24575
      int p = (int)(off_ull >> 13);          // plane 0..2
      long q = off_ull & 8191;
      ull* dst = (ull*)(H + (long)p*H_PL + 64L*65536) + q;
      __hip_atomic_store(dst, 0ULL, __ATOMIC_RELAXED, __HIP_MEMORY_SCOPE_AGENT);
    }
  }
  gbar(cnt, bar++);

  // encoder: slot_in = 63 + ((t+1)&1), slot_out = 63 + (t&1); t=0 reads zeroed slot 64
  for (int t = 0; t < Sv; ++t){
    if (rl)
      lstm_phase<false>(lb, tid, 63 + ((t+1)&1), 63 + (t&1), t,
          We0, We1, We2, b_e, src, (const int*)0, enc_emb,
          (const ull*)0, H, c, g4, hst, stok);
    gbar(cnt, bar++);
  }
  // decoder: step j reads slot (j==0 ? 64 : j-1), writes slot j
  for (int j = 0; j < Tv-1; ++j){
    if (rl)
      lstm_phase<true>(lb, tid, (j == 0) ? 64 : (j-1), j, j,
          Wd0, Wd1, Wd2, b_d, trg, tf, dec_emb, toku, H, c, g4, hst, stok);
    gbar(cnt, bar++);
    if (j < Tv-2 && tf[j+1] == 0){
      if (b < 500){
        const unsigned short* h0 = H + (long)j*65536;
        fc_phase(b, tid, h0, h0 + H_PL, Wfhi, Wflo, bfc, toku + (long)j*64, amax);
      }
      gbar(cnt, bar++);
    }
  }
}

// ---------------- batched logits: 4 j per block, grid (500,16), fragment-ordered ----------------
__global__ __launch_bounds__(256) void k_fcall(
    const unsigned short* __restrict__ Wfhi, const unsigned short* __restrict__ Wflo,
    const float* __restrict__ bfc,
    const unsigned short* __restrict__ H, float* __restrict__ out)
{
  const int tid = threadIdx.x;
  const int wv = tid >> 6, lane = tid & 63;
  const int l15 = lane & 15, lk = lane >> 4;
  const int vt = blockIdx.x*4 + wv;
  const int vcol = vt*16 + l15;
  const int jbase = blockIdx.y*4;
  const unsigned short* h0b = H + (long)jbase*65536;
  const unsigned short* h1b = h0b + H_PL;

  f32x4 acc[4][4];
  #pragma unroll
  for (int jj=0;jj<4;++jj)
    #pragma unroll
    for (int mt=0;mt<4;++mt) acc[jj][mt] = (f32x4){0.f,0.f,0.f,0.f};

  for (int kt = 0; kt < 32; ++kt){
    const long wo = (((long)vt*32 + kt) << 9) + (lane << 3);
    bf16x8 bh = *(const bf16x8*)(Wfhi + wo);
    bf16x8 bl = *(const bf16x8*)(Wflo + wo);
    #pragma unroll
    for (int jj=0;jj<4;++jj){
      if (jbase + jj <= 62){
        #pragma unroll
        for (int mt=0;mt<4;++mt){
          const long ho = (long)jj*65536 + (((long)mt*32 + kt) << 9) + (lane << 3);
          bf16x8 ah = *(const bf16x8*)(h0b + ho);
          bf16x8 al = *(const bf16x8*)(h1b + ho);
          acc[jj][mt] = MF(ah, bh, acc[jj][mt]);
          acc[jj][mt] = MF(al, bh, acc[jj][mt]);
          acc[jj][mt] = MF(ah, bl, acc[jj][mt]);
        }
      }
    }
  }
  float bb = bfc[vcol];
  #pragma unroll
  for (int jj=0;jj<4;++jj){
    if (jbase + jj <= 62){
      #pragma unroll
      for (int mt=0;mt<4;++mt){
        #pragma unroll
        for (int r=0;r<4;++r){
          int m = mt*16 + lk*4 + r;
          out[((long)m*Tv + (jbase+jj+1))*(long)Vv + vcol] = acc[jj][mt][r] + bb;
        }
      }
    }
  }
  if (blockIdx.y == 0){
    const int vb = blockIdx.x*64;
    for (int i = tid; i < 4096; i += 256){
      int m = i >> 6, v = vb + (i & 63);
      out[(long)m*Tv*(long)Vv + v] = 0.f;
    }
  }
}

// ---------------- fallback (round-2 proven path, used only if ws too small) ----------------

__global__ __launch_bounds__(256) void k_initC(float* __restrict__ ws, float* __restrict__ out){
  long i = (long)blockIdx.x*256 + threadIdx.x;
  if (i < 262144){ ws[i] = 0.f; }
  else {
    long r = i - 262144;
    long m = r / Vv, v = r % Vv;
    out[m*Tv*(long)Vv + v] = 0.f;
  }
}

__global__ __launch_bounds__(256) void k_stepC(
    int mode, int t,
    const int* __restrict__ tok_src, const int* __restrict__ tf_mask,
    const int* __restrict__ token_buf, const float* __restrict__ emb,
    const float* __restrict__ Wih, const float* __restrict__ Whh,
    const float* __restrict__ bias,
    const float* __restrict__ h_in, const float* __restrict__ c_in,
    float* __restrict__ h_out, float* __restrict__ c_out,
    unsigned short* __restrict__ hsp_hi, unsigned short* __restrict__ hsp_lo)
{
  __shared__ __align__(16) float tile[8*1536];
  __shared__ float gbuf[4*8*32];
  __shared__ int toks[8];
  const int tid = threadIdx.x;
  const int m0 = blockIdx.y*8, jh0 = blockIdx.x*32;
  if (tid < 8){
    int m = m0 + tid; int tok;
    if (mode == 0) tok = tok_src[m*Sv + t];
    else { if (t == 0) tok = tok_src[m*Tv];
           else tok = (tf_mask[t] > 0) ? tok_src[m*Tv + t] : token_buf[m]; }
    toks[tid] = tok;
  }
  __syncthreads();
  { float4* t4 = (float4*)tile;
    #pragma unroll
    for (int r = 0; r < 12; ++r){
      int f = tid + 256*r; int row = f / 384, o = f % 384; float4 v;
      if (o < 128) v = ((const float4*)(emb + (long)toks[row]*Ed))[o];
      else         v = ((const float4*)(h_in + (long)(m0+row)*Hd))[o-128];
      t4[row*384 + o] = v; } }
  __syncthreads();
  const int g = tid >> 6, sx = tid & 63, jl = sx & 31, mg = sx >> 5;
  const int col = g*Hd + jh0 + jl;
  const float4* wx = (const float4*)(Wih + (long)col*Ed);
  const float4* wh = (const float4*)(Whh + (long)col*Hd);
  const float4* t4 = (const float4*)tile;
  const int mb = mg*4;
  float bq = bias[col];
  float a0=bq, a1=bq, a2=bq, a3=bq;
  for (int k = 0; k < 128; ++k){
    float4 w = wx[k];
    float4 v0 = t4[(mb+0)*384 + k]; float4 v1 = t4[(mb+1)*384 + k];
    float4 v2 = t4[(mb+2)*384 + k]; float4 v3 = t4[(mb+3)*384 + k];
    a0 += w.x*v0.x + w.y*v0.y + w.z*v0.z + w.w*v0.w;
    a1 += w.x*v1.x + w.y*v1.y + w.z*v1.z + w.w*v1.w;
    a2 += w.x*v2.x + w.y*v2.y + w.z*v2.z + w.w*v2.w;
    a3 += w.x*v3.x + w.y*v3.y + w.z*v3.z + w.w*v3.w;
  }
  for (int k = 0; k < 256; ++k){
    float4 w = wh[k];
    float4 v0 = t4[(mb+0)*384 + 128 + k]; float4 v1 = t4[(mb+1)*384 + 128 + k];
    float4 v2 = t4[(mb+2)*384 + 128 + k]; float4 v3 = t4[(mb+3)*384 + 128 + k];
    a0 += w.x*v0.x + w.y*v0.y + w.z*v0.z + w.w*v0.w;
    a1 += w.x*v1.x + w.y*v1.y + w.z*v1.z + w.w*v1.w;
    a2 += w.x*v2.x + w.y*v2.y + w.z*v2.z + w.w*v2.w;
    a3 += w.x*v3.x + w.y*v3.y + w.z*v3.z + w.w*v3.w;
  }
  gbuf[g*256 + (mb+0)*32 + jl] = a0; gbuf[g*256 + (mb+1)*32 + jl] = a1;
  gbuf[g*256 + (mb+2)*32 + jl] = a2; gbuf[g*256 + (mb+3)*32 + jl] = a3;
  __syncthreads();
  const int ml = tid >> 5, j2 = tid & 31;
  float ig = gbuf[0*256 + ml*32 + j2];
  float fg = gbuf[1*256 + ml*32 + j2];
  float gg = gbuf[2*256 + ml*32 + j2];
  float og = gbuf[3*256 + ml*32 + j2];
  long idx = (long)(m0+ml)*Hd + jh0 + j2;
  float cc = c_in[idx];
  float cn = sigf(fg)*cc + sigf(ig)*tanhf(gg);
  float hn = sigf(og)*tanhf(cn);
  c_out[idx] = cn; h_out[idx] = hn;
  unsigned short hh = f2bf(hn);
  hsp_hi[idx] = hh; hsp_lo[idx] = f2bf(hn - bf2f(hh));
}

__global__ __launch_bounds__(256) void k_fcC(
    int j, const unsigned short* __restrict__ hhi, const unsigned short* __restrict__ hlo,
    const float* __restrict__ Wfc, const float* __restrict__ bfc, float* __restrict__ out)
{
  const int tid = threadIdx.x;
  const int wv = tid >> 6, lane = tid & 63;
  const int l15 = lane & 15, lk = lane >> 4;
  const int vcol = blockIdx.x*64 + wv*16 + l15;
  const float* wrow = Wfc + (long)vcol*Hd;
  f32x4 acc[4];
  #pragma unroll
  for (int mt=0; mt<4; ++mt) acc[mt] = (f32x4){0.f,0.f,0.f,0.f};
  #pragma unroll 2
  for (int kt = 0; kt < 32; ++kt){
    const int k0 = kt*32 + lk*8;
    float4 wa = *(const float4*)(wrow + k0);
    float4 wb = *(const float4*)(wrow + k0 + 4);
    float wf[8] = {wa.x,wa.y,wa.z,wa.w,wb.x,wb.y,wb.z,wb.w};
    bf16x8 bh, bl;
    #pragma unroll
    for (int e=0;e<8;++e){
      unsigned short h = f2bf(wf[e]);
      bh[e] = (short)h; bl[e] = (short)f2bf(wf[e] - bf2f(h));
    }
    #pragma unroll
    for (int mt=0; mt<4; ++mt){
      const int row = mt*16 + l15;
      bf16x8 ah = *(const bf16x8*)(hhi + row*Hd + k0);
      bf16x8 al = *(const bf16x8*)(hlo + row*Hd + k0);
      acc[mt] = MF(ah, bh, acc[mt]);
      acc[mt] = MF(al, bh, acc[mt]);
      acc[mt] = MF(ah, bl, acc[mt]);
    }
  }
  float bb = bfc[vcol];
  #pragma unroll
  for (int mt=0; mt<4; ++mt)
    #pragma unroll
    for (int r=0; r<4; ++r){
      int m = mt*16 + lk*4 + r;
      out[((long)m*Tv + (j+1))*(long)Vv + vcol] = acc[mt][r] + bb;
    }
}

__global__ __launch_bounds__(256) void k_argmaxC(
    int j, const float* __restrict__ out, int* __restrict__ token_buf)
{
  __shared__ float sval[256];
  __shared__ int   sidx[256];
  const int m = blockIdx.x, tid = threadIdx.x;
  const float* base = out + ((long)m*Tv + (j+1))*(long)Vv;
  float best = -INFINITY; int bi = 0;
  for (int v = tid; v < Vv; v += 256){
    float f = base[v];
    if (f > best){ best = f; bi = v; }
  }
  sval[tid] = best; sidx[tid] = bi;
  __syncthreads();
  for (int s2 = 128; s2 > 0; s2 >>= 1){
    if (tid < s2){
      float ov = sval[tid+s2]; int oi = sidx[tid+s2];
      if (ov > sval[tid] || (ov == sval[tid] && oi < sidx[tid])){
        sval[tid] = ov; sidx[tid] = oi;
      }
    }
    __syncthreads();
  }
  if (tid == 0) token_buf[m] = sidx[0];
}

extern "C" void kernel_launch(void* const* d_in, const int* in_sizes, int n_in,
                              void* d_out, int out_size, void* d_ws, size_t ws_size,
                              hipStream_t stream)
{
  const int*   src     = (const int*)  d_in[0];
  const int*   trg     = (const int*)  d_in[1];
  const int*   tf      = (const int*)  d_in[2];
  const float* enc_emb = (const float*)d_in[3];
  const float* dec_emb = (const float*)d_in[4];
  const float* Wih_e   = (const float*)d_in[5];
  const float* Whh_e   = (const float*)d_in[6];
  const float* b_e     = (const float*)d_in[7];
  const float* Wih_d   = (const float*)d_in[8];
  const float* Whh_d   = (const float*)d_in[9];
  const float* b_d     = (const float*)d_in[10];
  const float* Wfc     = (const float*)d_in[11];
  const float* bfc     = (const float*)d_in[12];
  float* out = (float*)d_out;
  float* ws  = (float*)d_ws;

  if (ws_size >= (size_t)NEED_FL * 4ULL){
    unsigned short* We0 = (unsigned short*)(ws + OFF_WE);
    unsigned short* Wd0 = (unsigned short*)(ws + OFF_WD);
    unsigned short* Wf0 = (unsigned short*)(ws + OFF_WF);
    unsigned short* Hb  = (unsigned short*)(ws + OFF_H);

    hipMemsetAsync((void*)(ws + OFF_TOK), 0, (size_t)(NEED_FL - OFF_TOK) * 4ULL, stream);
    k_wsplit3<<<4096, 256, 0, stream>>>(Wih_e, Whh_e, We0, We0 + W_PL, We0 + 2*W_PL);
    k_wsplit3<<<4096, 256, 0, stream>>>(Wih_d, Whh_d, Wd0, Wd0 + W_PL, Wd0 + 2*W_PL);
    k_wfsplit<<<32000, 256, 0, stream>>>(Wfc, Wf0, Wf0 + WF_PL);
    k_mega<<<NB, 256, 0, stream>>>(src, trg, tf, enc_emb, dec_emb, b_e, b_d, bfc, ws);
    k_fcall<<<dim3(500, 16), 256, 0, stream>>>(Wf0, Wf0 + WF_PL, bfc, Hb, out);
  } else {
    // fallback: round-2 proven multi-kernel path
    float* hbuf[2] = { ws,            ws + 65536 };
    float* cbuf[2] = { ws + 131072,   ws + 196608 };
    int*   tokbuf  = (int*)(ws + 262144);
    unsigned short* hsp_hi = (unsigned short*)(ws + 262208);
    unsigned short* hsp_lo = (unsigned short*)(ws + 262208 + 32768);

    k_initC<<<9024, 256, 0, stream>>>(ws, out);
    int cur = 0;
    for (int t = 0; t < Sv; ++t){
      k_stepC<<<dim3(32,8), 256, 0, stream>>>(0, t, src, tf, tokbuf, enc_emb,
          Wih_e, Whh_e, b_e, hbuf[cur], cbuf[cur], hbuf[cur^1], cbuf[cur^1], hsp_hi, hsp_lo);
      cur ^= 1;
    }
    for (int j = 0; j < Tv-1; ++j){
      k_stepC<<<dim3(32,8), 256, 0, stream>>>(1, j, trg, tf, tokbuf, dec_emb,
          Wih_d, Whh_d, b_d, hbuf[cur], cbuf[cur], hbuf[cur^1], cbuf[cur^1], hsp_hi, hsp_lo);
      cur ^= 1;
      k_fcC<<<500, 256, 0, stream>>>(j, hsp_hi, hsp_lo, Wfc, bfc, out);
      if (j < Tv-2) k_argmaxC<<<64, 256, 0, stream>>>(j, out, tokbuf);
    }
  }
}

// Round 15
// 9028.030 us; speedup vs baseline: 1.3130x; 1.2903x over previous
//
#include <hip/hip_runtime.h>
#include <math.h>

#define Hd 1024
#define Ed 512
#define Bv 64
#define Sv 128
#define Tv 64
#define Vv 32000
#define NB 256

typedef __attribute__((ext_vector_type(8))) short bf16x8;
typedef __attribute__((ext_vector_type(4))) float f32x4;
typedef unsigned long long ull;

__device__ __forceinline__ float sigf(float x){ return 1.0f/(1.0f + expf(-x)); }
__device__ __forceinline__ unsigned short f2bf(float f){
  unsigned u = __float_as_uint(f);
  return (unsigned short)((u + 0x7FFFu + ((u>>16)&1u)) >> 16);
}
__device__ __forceinline__ float bf2f(unsigned short b){ return __uint_as_float(((unsigned)b)<<16); }
__device__ __forceinline__ void split3(float v, unsigned short& s0, unsigned short& s1, unsigned short& s2){
  s0 = f2bf(v);
  float r1 = v - bf2f(s0);
  s1 = f2bf(r1);
  s2 = f2bf(r1 - bf2f(s1));
}
#define MF(A,B,C) __builtin_amdgcn_mfma_f32_16x16x32_bf16(A,B,C,0,0,0)

// ---- ws layout (float offsets) — fragment-ordered planes (round 12) ----
#define OFF_H    65536
#define H_PL     4259840L    // shorts per H plane (65 slots * 65536)
#define OFF_WE   6455296
#define OFF_WD   15892480
#define W_PL     6291456L    // shorts per W plane
#define OFF_WF   25329664
#define WF_PL    32768000L   // shorts per Wf plane
#define OFF_TOK  58097664
#define OFF_CNT  58105728
#define NEED_FL  58106240    // 232.4 MB

// ---------------- prep kernels (fragment-ordered planes) ----------------

__global__ __launch_bounds__(256) void k_wsplit3(
    const float* __restrict__ Wih, const float* __restrict__ Whh,
    unsigned short* __restrict__ d0, unsigned short* __restrict__ d1, unsigned short* __restrict__ d2)
{
  const int n = blockIdx.x;            // 0..4095
  const int tid = threadIdx.x;
  const int g = n >> 10, jt = (n & 1023) >> 4, nl = n & 15;
  const long base = ((long)(g*64 + jt)*48) << 9;
  #pragma unroll
  for (int i = 0; i < 6; ++i){
    int k = tid + 256*i;               // 0..1535
    float v = (k < 512) ? Wih[(long)n*512 + k] : Whh[(long)n*1024 + (k-512)];
    int kt = k >> 5, lk = (k >> 3) & 3, ke = k & 7;
    long dst = base + ((long)kt << 9) + ((lk*16 + nl) << 3) + ke;
    unsigned short s0,s1,s2; split3(v, s0,s1,s2);
    d0[dst] = s0; d1[dst] = s1; d2[dst] = s2;
  }
}

__global__ __launch_bounds__(256) void k_wfsplit(
    const float* __restrict__ W, unsigned short* __restrict__ dhi, unsigned short* __restrict__ dlo)
{
  const int v = blockIdx.x;            // 0..31999
  const int tid = threadIdx.x;
  const int vt = v >> 4, vl = v & 15;
  const long base = ((long)vt*32) << 9;
  #pragma unroll
  for (int i = 0; i < 4; ++i){
    int k = tid + 256*i;               // 0..1023
    float x = W[(long)v*1024 + k];
    int kt = k >> 5, lk = (k >> 3) & 3, ke = k & 7;
    long dst = base + ((long)kt << 9) + ((lk*16 + vl) << 3) + ke;
    unsigned short h = f2bf(x);
    dhi[dst] = h;
    dlo[dst] = f2bf(x - bf2f(h));
  }
}

// ---------------- grid barrier (256 arrivals, relaxed poll, workgroup-only acquire) ----------------
__device__ __forceinline__ void gbar(int* cnt, int idx){
  __syncthreads();
  if (threadIdx.x == 0){
    __hip_atomic_fetch_add(&cnt[idx], 1, __ATOMIC_RELEASE, __HIP_MEMORY_SCOPE_AGENT);
    while (__hip_atomic_load(&cnt[idx], __ATOMIC_RELAXED, __HIP_MEMORY_SCOPE_AGENT) < NB)
      __builtin_amdgcn_s_sleep(2);
    __builtin_amdgcn_fence(__ATOMIC_ACQUIRE, "workgroup");
  }
  __syncthreads();
}

// ---------------- LSTM phase: waves 0-3 active (bitwise r12 path), waves 4-7 pass through ----------------
template<bool DEC>
__device__ __forceinline__ void lstm_phase(
    int lb, int tid, int slot_in, int slot_out, int tj,
    const unsigned short* __restrict__ W0s, const unsigned short* __restrict__ W1s,
    const unsigned short* __restrict__ W2s, const float* __restrict__ bias,
    const int* __restrict__ tok_src, const int* __restrict__ tf,
    const float* __restrict__ emb, const ull* __restrict__ toku,
    unsigned short* __restrict__ H, float* __restrict__ c,
    float (*g4)[16][16], short (*hst)[16][16], int* stok)
{
  const bool act = (tid < 256);
  const int g = (tid >> 6) & 3, lane = tid & 63;
  const int l15 = lane & 15, lk = lane >> 4;
  const int jh = (lb & 63) * 16;
  const int m0 = (lb >> 6) * 16;
  const int mt = lb >> 6;
  const long wbase = ((long)(g*64 + (lb & 63))*48) << 9;
  const unsigned short* w0 = W0s + wbase;
  const unsigned short* w1 = W1s + wbase;
  const unsigned short* w2 = W2s + wbase;
  const unsigned short* h0 = H + (long)slot_in*65536;
  const unsigned short* h1 = h0 + H_PL;
  const unsigned short* h2 = h0 + 2*H_PL;

  if (tid < 16){
    int m = m0 + tid, tk;
    if (!DEC){
      tk = tok_src[m*Sv + tj];
    } else {
      if (tj == 0) tk = tok_src[m*Tv];
      else if (tf[tj] > 0) tk = tok_src[m*Tv + tj];
      else tk = (int)(~(unsigned)__hip_atomic_load(&toku[(long)(tj-1)*64 + m],
                     __ATOMIC_RELAXED, __HIP_MEMORY_SCOPE_AGENT));
    }
    stok[tid] = tk;
  }
  __syncthreads();

  if (act){
    f32x4 acc = (f32x4){0.f,0.f,0.f,0.f};

    // x part: K = 0..511 (W kt 0..15); emb gathered+split on the fly
    {
      const float* e0 = emb + (long)stok[l15]*Ed;
      #pragma unroll 2
      for (int kt = 0; kt < 16; ++kt){
        const int k0 = kt*32 + lk*8;
        bf16x8 b0  = *(const bf16x8*)(w0 + ((long)kt << 9) + (lane << 3));
        bf16x8 b1v = *(const bf16x8*)(w1 + ((long)kt << 9) + (lane << 3));
        bf16x8 b2  = *(const bf16x8*)(w2 + ((long)kt << 9) + (lane << 3));
        bf16x8 a0,a1,a2;
        float4 pa = *(const float4*)(e0 + k0);
        float4 pb = *(const float4*)(e0 + k0 + 4);
        float fv[8] = {pa.x,pa.y,pa.z,pa.w,pb.x,pb.y,pb.z,pb.w};
        #pragma unroll
        for (int e=0;e<8;++e){ unsigned short s0,s1,s2; split3(fv[e],s0,s1,s2);
          a0[e]=(short)s0; a1[e]=(short)s1; a2[e]=(short)s2; }
        acc = MF(a0,b0,acc); acc = MF(a1,b0,acc); acc = MF(a0,b1v,acc);
        acc = MF(a2,b0,acc); acc = MF(a0,b2,acc); acc = MF(a1,b1v,acc);
      }
    }
    // h part: K = 512..1535 (W kt 16..47; H kt 0..31, fragment-ordered)
    {
      #pragma unroll 2
      for (int kt = 0; kt < 32; ++kt){
        bf16x8 b0  = *(const bf16x8*)(w0 + ((long)(16+kt) << 9) + (lane << 3));
        bf16x8 b1v = *(const bf16x8*)(w1 + ((long)(16+kt) << 9) + (lane << 3));
        bf16x8 b2  = *(const bf16x8*)(w2 + ((long)(16+kt) << 9) + (lane << 3));
        const long ho = (((long)mt*32 + kt) << 9) + (lane << 3);
        bf16x8 a0 = *(const bf16x8*)(h0 + ho);
        bf16x8 a1 = *(const bf16x8*)(h1 + ho);
        bf16x8 a2 = *(const bf16x8*)(h2 + ho);
        acc = MF(a0,b0,acc); acc = MF(a1,b0,acc); acc = MF(a0,b1v,acc);
        acc = MF(a2,b0,acc); acc = MF(a0,b2,acc); acc = MF(a1,b1v,acc);
      }
    }

    #pragma unroll
    for (int r = 0; r < 4; ++r) g4[g][lk*4 + r][l15] = acc[r];
  }
  __syncthreads();

  if (act){
    const int mloc = tid >> 4, cl = tid & 15;
    const int col = jh + cl;
    float ig = g4[0][mloc][cl] + bias[col];
    float fg = g4[1][mloc][cl] + bias[Hd + col];
    float gg = g4[2][mloc][cl] + bias[2*Hd + col];
    float og = g4[3][mloc][cl] + bias[3*Hd + col];
    long idx = (long)(m0 + mloc)*Hd + col;
    float cv = c[idx];
    float cn = sigf(fg)*cv + sigf(ig)*tanhf(gg);
    float hn = sigf(og)*tanhf(cn);
    c[idx] = cn;
    unsigned short s0,s1,s2; split3(hn, s0,s1,s2);
    hst[0][mloc][cl] = (short)s0; hst[1][mloc][cl] = (short)s1; hst[2][mloc][cl] = (short)s2;
  }
  __syncthreads();
  // write-once H slot_out, fragment order: element (m=m0+r, k=jh+q*4+i)
  if (tid < 192){
    const int p = tid >> 6, t2 = tid & 63, r = t2 >> 2, q = t2 & 3;
    ull v =
        (ull)(unsigned short)hst[p][r][q*4]
      | ((ull)(unsigned short)hst[p][r][q*4+1] << 16)
      | ((ull)(unsigned short)hst[p][r][q*4+2] << 32)
      | ((ull)(unsigned short)hst[p][r][q*4+3] << 48);
    const int kt = (lb & 63) >> 1;
    const int off16 = (jh & 16) + q*4;            // 0..28
    const int lkw = off16 >> 3, keb = off16 & 7;  // keb in {0,4}
    ull* dst = (ull*)(H + (long)p*H_PL + (long)slot_out*65536
                      + (((long)mt*32 + kt) << 9) + ((lkw*16 + r) << 3) + keb);
    __hip_atomic_store(dst, v, __ATOMIC_RELAXED, __HIP_MEMORY_SCOPE_AGENT);
  }
}

// ---------------- argmax-only FC phase: 250 blocks x 8 waves x 16 vocab ----------------
// Per-accumulator MFMA sequence identical to rounds 13/14: per kt, (ah,bh),(al,bh),(ah,bl).
__device__ __forceinline__ void fc_phase(
    int b, int tid,
    const unsigned short* __restrict__ hhi, const unsigned short* __restrict__ hlo,
    const unsigned short* __restrict__ Wfhi, const unsigned short* __restrict__ Wflo,
    const float* __restrict__ bfc,
    ull* __restrict__ tslot, ull* amax)
{
  if (tid < 64) amax[tid] = 0ULL;
  __syncthreads();
  const int wv = tid >> 6, lane = tid & 63;
  const int l15 = lane & 15, lk = lane >> 4;
  const int vt = b*8 + wv;               // 0..1999
  const int v0 = vt*16 + l15;

  f32x4 acc[4];
  #pragma unroll
  for (int mt=0; mt<4; ++mt) acc[mt] = (f32x4){0.f,0.f,0.f,0.f};

  #pragma unroll 2
  for (int kt = 0; kt < 32; ++kt){
    const long wo = (((long)vt*32 + kt) << 9) + (lane << 3);
    bf16x8 bh = *(const bf16x8*)(Wfhi + wo);
    bf16x8 bl = *(const bf16x8*)(Wflo + wo);
    #pragma unroll
    for (int mt=0; mt<4; ++mt){
      const long ho = (((long)mt*32 + kt) << 9) + (lane << 3);
      bf16x8 ah = *(const bf16x8*)(hhi + ho);
      bf16x8 al = *(const bf16x8*)(hlo + ho);
      acc[mt] = MF(ah, bh, acc[mt]);
      acc[mt] = MF(al, bh, acc[mt]);
      acc[mt] = MF(ah, bl, acc[mt]);
    }
  }
  float bb0 = bfc[v0];
  #pragma unroll
  for (int mt=0; mt<4; ++mt){
    #pragma unroll
    for (int r=0; r<4; ++r){
      int m = mt*16 + lk*4 + r;
      float f0 = acc[mt][r] + bb0;
      unsigned u0 = __float_as_uint(f0); u0 ^= (u0 >> 31) ? 0xFFFFFFFFu : 0x80000000u;
      ull cm = ((ull)u0 << 32) | (unsigned)(~v0);
      #pragma unroll
      for (int d=1; d<16; d<<=1){
        ull o = __shfl_xor(cm, d);
        if (o > cm) cm = o;
      }
      if (l15 == 0) atomicMax(&amax[m], cm);
    }
  }
  __syncthreads();
  if (tid < 64) atomicMax(tslot + tid, amax[tid]);
}

// ---------------- the mega kernel: 256 blocks x 512 threads (8 waves/CU, 256-arrival barrier) ----------------
__global__ __launch_bounds__(512, 1) void k_mega(
    const int* __restrict__ src, const int* __restrict__ trg, const int* __restrict__ tf,
    const float* __restrict__ enc_emb, const float* __restrict__ dec_emb,
    const float* __restrict__ b_e, const float* __restrict__ b_d,
    const float* __restrict__ bfc,
    float* __restrict__ ws)
{
  __shared__ float g4[4][16][16];
  __shared__ short hst[3][16][16];
  __shared__ int stok[16];
  __shared__ ull amax[64];

  const int b = blockIdx.x, tid = threadIdx.x;
  const int lb = b;

  float* c = ws;
  unsigned short* H = (unsigned short*)(ws + OFF_H);
  const unsigned short* We0 = (const unsigned short*)(ws + OFF_WE);
  const unsigned short* We1 = We0 + W_PL;
  const unsigned short* We2 = We0 + 2*W_PL;
  const unsigned short* Wd0 = (const unsigned short*)(ws + OFF_WD);
  const unsigned short* Wd1 = Wd0 + W_PL;
  const unsigned short* Wd2 = Wd0 + 2*W_PL;
  const unsigned short* Wfhi = (const unsigned short*)(ws + OFF_WF);
  const unsigned short* Wflo = Wfhi + WF_PL;
  ull* toku = (ull*)(ws + OFF_TOK);
  int* cnt = (int*)(ws + OFF_CNT);
  int bar = 0;

  // init: zero own c tile + stripe of H slot 64 (3 planes x 8192 ULL = 256 blocks x 96)
  if (tid < 256){
    const int jh = (lb & 63)*16, m0 = (lb >> 6)*16;
    const int mloc = tid >> 4, cl = tid & 15;
    c[(long)(m0+mloc)*Hd + jh + cl] = 0.f;
    if (tid < 96){
      long off_ull = (long)lb*96 + tid;      // 0 .. 24575
      int p = (int)(off_ull >> 13);          // plane 0..2
      long q = off_ull & 8191;
      ull* dst = (ull*)(H + (long)p*H_PL + 64L*65536) + q;
      __hip_atomic_store(dst, 0ULL, __ATOMIC_RELAXED, __HIP_MEMORY_SCOPE_AGENT);
    }
  }
  gbar(cnt, bar++);

  // encoder: slot_in = 63 + ((t+1)&1), slot_out = 63 + (t&1); t=0 reads zeroed slot 64
  for (int t = 0; t < Sv; ++t){
    lstm_phase<false>(lb, tid, 63 + ((t+1)&1), 63 + (t&1), t,
        We0, We1, We2, b_e, src, (const int*)0, enc_emb,
        (const ull*)0, H, c, g4, hst, stok);
    gbar(cnt, bar++);
  }
  // decoder: step j reads slot (j==0 ? 64 : j-1), writes slot j
  for (int j = 0; j < Tv-1; ++j){
    lstm_phase<true>(lb, tid, (j == 0) ? 64 : (j-1), j, j,
        Wd0, Wd1, Wd2, b_d, trg, tf, dec_emb, toku, H, c, g4, hst, stok);
    gbar(cnt, bar++);
    if (j < Tv-2 && tf[j+1] == 0){
      if (b < 250){
        const unsigned short* h0 = H + (long)j*65536;
        fc_phase(b, tid, h0, h0 + H_PL, Wfhi, Wflo, bfc, toku + (long)j*64, amax);
      }
      gbar(cnt, bar++);
    }
  }
}

// ---------------- batched logits: 4 j per block, grid (500,16), fragment-ordered ----------------
__global__ __launch_bounds__(256) void k_fcall(
    const unsigned short* __restrict__ Wfhi, const unsigned short* __restrict__ Wflo,
    const float* __restrict__ bfc,
    const unsigned short* __restrict__ H, float* __restrict__ out)
{
  const int tid = threadIdx.x;
  const int wv = tid >> 6, lane = tid & 63;
  const int l15 = lane & 15, lk = lane >> 4;
  const int vt = blockIdx.x*4 + wv;
  const int vcol = vt*16 + l15;
  const int jbase = blockIdx.y*4;
  const unsigned short* h0b = H + (long)jbase*65536;
  const unsigned short* h1b = h0b + H_PL;

  f32x4 acc[4][4];
  #pragma unroll
  for (int jj=0;jj<4;++jj)
    #pragma unroll
    for (int mt=0;mt<4;++mt) acc[jj][mt] = (f32x4){0.f,0.f,0.f,0.f};

  for (int kt = 0; kt < 32; ++kt){
    const long wo = (((long)vt*32 + kt) << 9) + (lane << 3);
    bf16x8 bh = *(const bf16x8*)(Wfhi + wo);
    bf16x8 bl = *(const bf16x8*)(Wflo + wo);
    #pragma unroll
    for (int jj=0;jj<4;++jj){
      if (jbase + jj <= 62){
        #pragma unroll
        for (int mt=0;mt<4;++mt){
          const long ho = (long)jj*65536 + (((long)mt*32 + kt) << 9) + (lane << 3);
          bf16x8 ah = *(const bf16x8*)(h0b + ho);
          bf16x8 al = *(const bf16x8*)(h1b + ho);
          acc[jj][mt] = MF(ah, bh, acc[jj][mt]);
          acc[jj][mt] = MF(al, bh, acc[jj][mt]);
          acc[jj][mt] = MF(ah, bl, acc[jj][mt]);
        }
      }
    }
  }
  float bb = bfc[vcol];
  #pragma unroll
  for (int jj=0;jj<4;++jj){
    if (jbase + jj <= 62){
      #pragma unroll
      for (int mt=0;mt<4;++mt){
        #pragma unroll
        for (int r=0;r<4;++r){
          int m = mt*16 + lk*4 + r;
          out[((long)m*Tv + (jbase+jj+1))*(long)Vv + vcol] = acc[jj][mt][r] + bb;
        }
      }
    }
  }
  if (blockIdx.y == 0){
    const int vb = blockIdx.x*64;
    for (int i = tid; i < 4096; i += 256){
      int m = i >> 6, v = vb + (i & 63);
      out[(long)m*Tv*(long)Vv + v] = 0.f;
    }
  }
}

// ---------------- fallback (round-2 proven path, used only if ws too small) ----------------

__global__ __launch_bounds__(256) void k_initC(float* __restrict__ ws, float* __restrict__ out){
  long i = (long)blockIdx.x*256 + threadIdx.x;
  if (i < 262144){ ws[i] = 0.f; }
  else {
    long r = i - 262144;
    long m = r / Vv, v = r % Vv;
    out[m*Tv*(long)Vv + v] = 0.f;
  }
}

__global__ __launch_bounds__(256) void k_stepC(
    int mode, int t,
    const int* __restrict__ tok_src, const int* __restrict__ tf_mask,
    const int* __restrict__ token_buf, const float* __restrict__ emb,
    const float* __restrict__ Wih, const float* __restrict__ Whh,
    const float* __restrict__ bias,
    const float* __restrict__ h_in, const float* __restrict__ c_in,
    float* __restrict__ h_out, float* __restrict__ c_out,
    unsigned short* __restrict__ hsp_hi, unsigned short* __restrict__ hsp_lo)
{
  __shared__ __align__(16) float tile[8*1536];
  __shared__ float gbuf[4*8*32];
  __shared__ int toks[8];
  const int tid = threadIdx.x;
  const int m0 = blockIdx.y*8, jh0 = blockIdx.x*32;
  if (tid < 8){
    int m = m0 + tid; int tok;
    if (mode == 0) tok = tok_src[m*Sv + t];
    else { if (t == 0) tok = tok_src[m*Tv];
           else tok = (tf_mask[t] > 0) ? tok_src[m*Tv + t] : token_buf[m]; }
    toks[tid] = tok;
  }
  __syncthreads();
  { float4* t4 = (float4*)tile;
    #pragma unroll
    for (int r = 0; r < 12; ++r){
      int f = tid + 256*r; int row = f / 384, o = f % 384; float4 v;
      if (o < 128) v = ((const float4*)(emb + (long)toks[row]*Ed))[o];
      else         v = ((const float4*)(h_in + (long)(m0+row)*Hd))[o-128];
      t4[row*384 + o] = v; } }
  __syncthreads();
  const int g = tid >> 6, sx = tid & 63, jl = sx & 31, mg = sx >> 5;
  const int col = g*Hd + jh0 + jl;
  const float4* wx = (const float4*)(Wih + (long)col*Ed);
  const float4* wh = (const float4*)(Whh + (long)col*Hd);
  const float4* t4 = (const float4*)tile;
  const int mb = mg*4;
  float bq = bias[col];
  float a0=bq, a1=bq, a2=bq, a3=bq;
  for (int k = 0; k < 128; ++k){
    float4 w = wx[k];
    float4 v0 = t4[(mb+0)*384 + k]; float4 v1 = t4[(mb+1)*384 + k];
    float4 v2 = t4[(mb+2)*384 + k]; float4 v3 = t4[(mb+3)*384 + k];
    a0 += w.x*v0.x + w.y*v0.y + w.z*v0.z + w.w*v0.w;
    a1 += w.x*v1.x + w.y*v1.y + w.z*v1.z + w.w*v1.w;
    a2 += w.x*v2.x + w.y*v2.y + w.z*v2.z + w.w*v2.w;
    a3 += w.x*v3.x + w.y*v3.y + w.z*v3.z + w.w*v3.w;
  }
  for (int k = 0; k < 256; ++k){
    float4 w = wh[k];
    float4 v0 = t4[(mb+0)*384 + 128 + k]; float4 v1 = t4[(mb+1)*384 + 128 + k];
    float4 v2 = t4[(mb+2)*384 + 128 + k]; float4 v3 = t4[(mb+3)*384 + 128 + k];
    a0 += w.x*v0.x + w.y*v0.y + w.z*v0.z + w.w*v0.w;
    a1 += w.x*v1.x + w.y*v1.y + w.z*v1.z + w.w*v1.w;
    a2 += w.x*v2.x + w.y*v2.y + w.z*v2.z + w.w*v2.w;
    a3 += w.x*v3.x + w.y*v3.y + w.z*v3.z + w.w*v3.w;
  }
  gbuf[g*256 + (mb+0)*32 + jl] = a0; gbuf[g*256 + (mb+1)*32 + jl] = a1;
  gbuf[g*256 + (mb+2)*32 + jl] = a2; gbuf[g*256 + (mb+3)*32 + jl] = a3;
  __syncthreads();
  const int ml = tid >> 5, j2 = tid & 31;
  float ig = gbuf[0*256 + ml*32 + j2];
  float fg = gbuf[1*256 + ml*32 + j2];
  float gg = gbuf[2*256 + ml*32 + j2];
  float og = gbuf[3*256 + ml*32 + j2];
  long idx = (long)(m0+ml)*Hd + jh0 + j2;
  float cc = c_in[idx];
  float cn = sigf(fg)*cc + sigf(ig)*tanhf(gg);
  float hn = sigf(og)*tanhf(cn);
  c_out[idx] = cn; h_out[idx] = hn;
  unsigned short hh = f2bf(hn);
  hsp_hi[idx] = hh; hsp_lo[idx] = f2bf(hn - bf2f(hh));
}

__global__ __launch_bounds__(256) void k_fcC(
    int j, const unsigned short* __restrict__ hhi, const unsigned short* __restrict__ hlo,
    const float* __restrict__ Wfc, const float* __restrict__ bfc, float* __restrict__ out)
{
  const int tid = threadIdx.x;
  const int wv = tid >> 6, lane = tid & 63;
  const int l15 = lane & 15, lk = lane >> 4;
  const int vcol = blockIdx.x*64 + wv*16 + l15;
  const float* wrow = Wfc + (long)vcol*Hd;
  f32x4 acc[4];
  #pragma unroll
  for (int mt=0; mt<4; ++mt) acc[mt] = (f32x4){0.f,0.f,0.f,0.f};
  #pragma unroll 2
  for (int kt = 0; kt < 32; ++kt){
    const int k0 = kt*32 + lk*8;
    float4 wa = *(const float4*)(wrow + k0);
    float4 wb = *(const float4*)(wrow + k0 + 4);
    float wf[8] = {wa.x,wa.y,wa.z,wa.w,wb.x,wb.y,wb.z,wb.w};
    bf16x8 bh, bl;
    #pragma unroll
    for (int e=0;e<8;++e){
      unsigned short h = f2bf(wf[e]);
      bh[e] = (short)h; bl[e] = (short)f2bf(wf[e] - bf2f(h));
    }
    #pragma unroll
    for (int mt=0; mt<4; ++mt){
      const int row = mt*16 + l15;
      bf16x8 ah = *(const bf16x8*)(hhi + row*Hd + k0);
      bf16x8 al = *(const bf16x8*)(hlo + row*Hd + k0);
      acc[mt] = MF(ah, bh, acc[mt]);
      acc[mt] = MF(al, bh, acc[mt]);
      acc[mt] = MF(ah, bl, acc[mt]);
    }
  }
  float bb = bfc[vcol];
  #pragma unroll
  for (int mt=0; mt<4; ++mt)
    #pragma unroll
    for (int r=0; r<4; ++r){
      int m = mt*16 + lk*4 + r;
      out[((long)m*Tv + (j+1))*(long)Vv + vcol] = acc[mt][r] + bb;
    }
}

__global__ __launch_bounds__(256) void k_argmaxC(
    int j, const float* __restrict__ out, int* __restrict__ token_buf)
{
  __shared__ float sval[256];
  __shared__ int   sidx[256];
  const int m = blockIdx.x, tid = threadIdx.x;
  const float* base = out + ((long)m*Tv + (j+1))*(long)Vv;
  float best = -INFINITY; int bi = 0;
  for (int v = tid; v < Vv; v += 256){
    float f = base[v];
    if (f > best){ best = f; bi = v; }
  }
  sval[tid] = best; sidx[tid] = bi;
  __syncthreads();
  for (int s2 = 128; s2 > 0; s2 >>= 1){
    if (tid < s2){
      float ov = sval[tid+s2]; int oi = sidx[tid+s2];
      if (ov > sval[tid] || (ov == sval[tid] && oi < sidx[tid])){
        sval[tid] = ov; sidx[tid] = oi;
      }
    }
    __syncthreads();
  }
  if (tid == 0) token_buf[m] = sidx[0];
}

extern "C" void kernel_launch(void* const* d_in, const int* in_sizes, int n_in,
                              void* d_out, int out_size, void* d_ws, size_t ws_size,
                              hipStream_t stream)
{
  const int*   src     = (const int*)  d_in[0];
  const int*   trg     = (const int*)  d_in[1];
  const int*   tf      = (const int*)  d_in[2];
  const float* enc_emb = (const float*)d_in[3];
  const float* dec_emb = (const float*)d_in[4];
  const float* Wih_e   = (const float*)d_in[5];
  const float* Whh_e   = (const float*)d_in[6];
  const float* b_e     = (const float*)d_in[7];
  const float* Wih_d   = (const float*)d_in[8];
  const float* Whh_d   = (const float*)d_in[9];
  const float* b_d     = (const float*)d_in[10];
  const float* Wfc     = (const float*)d_in[11];
  const float* bfc     = (const float*)d_in[12];
  float* out = (float*)d_out;
  float* ws  = (float*)d_ws;

  if (ws_size >= (size_t)NEED_FL * 4ULL){
    unsigned short* We0 = (unsigned short*)(ws + OFF_WE);
    unsigned short* Wd0 = (unsigned short*)(ws + OFF_WD);
    unsigned short* Wf0 = (unsigned short*)(ws + OFF_WF);
    unsigned short* Hb  = (unsigned short*)(ws + OFF_H);

    hipMemsetAsync((void*)(ws + OFF_TOK), 0, (size_t)(NEED_FL - OFF_TOK) * 4ULL, stream);
    k_wsplit3<<<4096, 256, 0, stream>>>(Wih_e, Whh_e, We0, We0 + W_PL, We0 + 2*W_PL);
    k_wsplit3<<<4096, 256, 0, stream>>>(Wih_d, Whh_d, Wd0, Wd0 + W_PL, Wd0 + 2*W_PL);
    k_wfsplit<<<32000, 256, 0, stream>>>(Wfc, Wf0, Wf0 + WF_PL);
    k_mega<<<NB, 512, 0, stream>>>(src, trg, tf, enc_emb, dec_emb, b_e, b_d, bfc, ws);
    k_fcall<<<dim3(500, 16), 256, 0, stream>>>(Wf0, Wf0 + WF_PL, bfc, Hb, out);
  } else {
    // fallback: round-2 proven multi-kernel path
    float* hbuf[2] = { ws,            ws + 65536 };
    float* cbuf[2] = { ws + 131072,   ws + 196608 };
    int*   tokbuf  = (int*)(ws + 262144);
    unsigned short* hsp_hi = (unsigned short*)(ws + 262208);
    unsigned short* hsp_lo = (unsigned short*)(ws + 262208 + 32768);

    k_initC<<<9024, 256, 0, stream>>>(ws, out);
    int cur = 0;
    for (int t = 0; t < Sv; ++t){
      k_stepC<<<dim3(32,8), 256, 0, stream>>>(0, t, src, tf, tokbuf, enc_emb,
          Wih_e, Whh_e, b_e, hbuf[cur], cbuf[cur], hbuf[cur^1], cbuf[cur^1], hsp_hi, hsp_lo);
      cur ^= 1;
    }
    for (int j = 0; j < Tv-1; ++j){
      k_stepC<<<dim3(32,8), 256, 0, stream>>>(1, j, trg, tf, tokbuf, dec_emb,
          Wih_d, Whh_d, b_d, hbuf[cur], cbuf[cur], hbuf[cur^1], cbuf[cur^1], hsp_hi, hsp_lo);
      cur ^= 1;
      k_fcC<<<500, 256, 0, stream>>>(j, hsp_hi, hsp_lo, Wfc, bfc, out);
      if (j < Tv-2) k_argmaxC<<<64, 256, 0, stream>>>(j, out, tokbuf);
    }
  }
}

// Round 16
// 8617.655 us; speedup vs baseline: 1.3755x; 1.0476x over previous
//
#include <hip/hip_runtime.h>
#include <math.h>

#define Hd 1024
#define Ed 512
#define Bv 64
#define Sv 128
#define Tv 64
#define Vv 32000
#define NB 256

typedef __attribute__((ext_vector_type(8))) short bf16x8;
typedef __attribute__((ext_vector_type(4))) float f32x4;
typedef unsigned long long ull;

__device__ __forceinline__ float sigf(float x){ return 1.0f/(1.0f + expf(-x)); }
__device__ __forceinline__ unsigned short f2bf(float f){
  unsigned u = __float_as_uint(f);
  return (unsigned short)((u + 0x7FFFu + ((u>>16)&1u)) >> 16);
}
__device__ __forceinline__ float bf2f(unsigned short b){ return __uint_as_float(((unsigned)b)<<16); }
__device__ __forceinline__ void split3(float v, unsigned short& s0, unsigned short& s1, unsigned short& s2){
  s0 = f2bf(v);
  float r1 = v - bf2f(s0);
  s1 = f2bf(r1);
  s2 = f2bf(r1 - bf2f(s1));
}
#define MF(A,B,C) __builtin_amdgcn_mfma_f32_16x16x32_bf16(A,B,C,0,0,0)

// ---- ws layout (float offsets) — fragment-ordered planes ----
#define OFF_H    65536
#define H_PL     4259840L    // shorts per H plane (65 slots * 65536)
#define OFF_WE   6455296
#define OFF_WD   15892480
#define W_PL     6291456L    // shorts per W plane
#define OFF_WF   25329664
#define WF_PL    32768000L   // shorts per Wf plane
#define OFF_TOK  58097664
#define OFF_CNT  58105728    // fcnt[128] | gcnt[4][256]
#define NEED_FL  58106880    // 232.4 MB (<= 233.2 MB proven)

// ---------------- prep kernels (fragment-ordered planes) ----------------

__global__ __launch_bounds__(256) void k_wsplit3(
    const float* __restrict__ Wih, const float* __restrict__ Whh,
    unsigned short* __restrict__ d0, unsigned short* __restrict__ d1, unsigned short* __restrict__ d2)
{
  const int n = blockIdx.x;            // 0..4095
  const int tid = threadIdx.x;
  const int g = n >> 10, jt = (n & 1023) >> 4, nl = n & 15;
  const long base = ((long)(g*64 + jt)*48) << 9;
  #pragma unroll
  for (int i = 0; i < 6; ++i){
    int k = tid + 256*i;               // 0..1535
    float v = (k < 512) ? Wih[(long)n*512 + k] : Whh[(long)n*1024 + (k-512)];
    int kt = k >> 5, lk = (k >> 3) & 3, ke = k & 7;
    long dst = base + ((long)kt << 9) + ((lk*16 + nl) << 3) + ke;
    unsigned short s0,s1,s2; split3(v, s0,s1,s2);
    d0[dst] = s0; d1[dst] = s1; d2[dst] = s2;
  }
}

__global__ __launch_bounds__(256) void k_wfsplit(
    const float* __restrict__ W, unsigned short* __restrict__ dhi, unsigned short* __restrict__ dlo)
{
  const int v = blockIdx.x;            // 0..31999
  const int tid = threadIdx.x;
  const int vt = v >> 4, vl = v & 15;
  const long base = ((long)vt*32) << 9;
  #pragma unroll
  for (int i = 0; i < 4; ++i){
    int k = tid + 256*i;               // 0..1023
    float x = W[(long)v*1024 + k];
    int kt = k >> 5, lk = (k >> 3) & 3, ke = k & 7;
    long dst = base + ((long)kt << 9) + ((lk*16 + vl) << 3) + ke;
    unsigned short h = f2bf(x);
    dhi[dst] = h;
    dlo[dst] = f2bf(x - bf2f(h));
  }
}

// ---------------- grid barrier, N arrivals (relaxed poll, workgroup-only acquire) ----------------
__device__ __forceinline__ void gbarN(int* cnt, int idx, int N){
  __syncthreads();
  if (threadIdx.x == 0){
    __hip_atomic_fetch_add(&cnt[idx], 1, __ATOMIC_RELEASE, __HIP_MEMORY_SCOPE_AGENT);
    while (__hip_atomic_load(&cnt[idx], __ATOMIC_RELAXED, __HIP_MEMORY_SCOPE_AGENT) < N)
      __builtin_amdgcn_s_sleep(2);
    __builtin_amdgcn_fence(__ATOMIC_ACQUIRE, "workgroup");
  }
  __syncthreads();
}

// ---------------- x-part precompute (waves 4-7): bitwise-identical x-loop ----------------
__device__ __forceinline__ void xpre(
    int lb, int tid, const float* __restrict__ nemb,
    const unsigned short* __restrict__ NW0, const unsigned short* __restrict__ NW1,
    const unsigned short* __restrict__ NW2,
    const int* __restrict__ stok2, float (*xgd)[64][4])
{
  const int g2 = (tid >> 6) & 3, lane = tid & 63;
  const int l15 = lane & 15, lk = lane >> 4;
  const long wb = ((long)(g2*64 + (lb & 63))*48) << 9;
  const unsigned short* w0 = NW0 + wb;
  const unsigned short* w1 = NW1 + wb;
  const unsigned short* w2 = NW2 + wb;
  f32x4 acc = (f32x4){0.f,0.f,0.f,0.f};
  const float* e0 = nemb + (long)stok2[l15]*Ed;
  #pragma unroll 2
  for (int kt = 0; kt < 16; ++kt){
    const int k0 = kt*32 + lk*8;
    bf16x8 b0  = *(const bf16x8*)(w0 + ((long)kt << 9) + (lane << 3));
    bf16x8 b1v = *(const bf16x8*)(w1 + ((long)kt << 9) + (lane << 3));
    bf16x8 b2  = *(const bf16x8*)(w2 + ((long)kt << 9) + (lane << 3));
    bf16x8 a0,a1,a2;
    float4 pa = *(const float4*)(e0 + k0);
    float4 pb = *(const float4*)(e0 + k0 + 4);
    float fv[8] = {pa.x,pa.y,pa.z,pa.w,pb.x,pb.y,pb.z,pb.w};
    #pragma unroll
    for (int e=0;e<8;++e){ unsigned short s0,s1,s2; split3(fv[e],s0,s1,s2);
      a0[e]=(short)s0; a1[e]=(short)s1; a2[e]=(short)s2; }
    acc = MF(a0,b0,acc); acc = MF(a1,b0,acc); acc = MF(a0,b1v,acc);
    acc = MF(a2,b0,acc); acc = MF(a0,b2,acc); acc = MF(a1,b1v,acc);
  }
  #pragma unroll
  for (int r = 0; r < 4; ++r) xgd[g2][lane][r] = acc[r];
}

// ---------------- LSTM phase: waves 0-3 compute (xg-seeded or full), waves 4-7 precompute next x ----------------
template<bool DEC>
__device__ __forceinline__ void lstm_phase(
    int lb, int tid, int slot_in, int slot_out, int tj,
    bool hasxg, int xb,
    int donext, const int* __restrict__ ntok, int nstride, int nidx,
    const float* __restrict__ nemb,
    const unsigned short* __restrict__ NW0, const unsigned short* __restrict__ NW1,
    const unsigned short* __restrict__ NW2,
    const unsigned short* __restrict__ W0s, const unsigned short* __restrict__ W1s,
    const unsigned short* __restrict__ W2s, const float* __restrict__ bias,
    const int* __restrict__ tok_src, const int* __restrict__ tf,
    const float* __restrict__ emb, const ull* __restrict__ toku,
    unsigned short* __restrict__ H, float* __restrict__ c,
    float (*g4)[16][16], short (*hst)[16][16], int* stok, int* stok2,
    float (*xg)[4][64][4])
{
  const bool act = (tid < 256);
  const int g = (tid >> 6) & 3, lane = tid & 63;
  const int l15 = lane & 15, lk = lane >> 4;
  const int jh = (lb & 63) * 16;
  const int m0 = (lb >> 6) * 16;
  const int mt = lb >> 6;
  const long wbase = ((long)(g*64 + (lb & 63))*48) << 9;
  const unsigned short* w0 = W0s + wbase;
  const unsigned short* w1 = W1s + wbase;
  const unsigned short* w2 = W2s + wbase;
  const unsigned short* h0 = H + (long)slot_in*65536;
  const unsigned short* h1 = h0 + H_PL;
  const unsigned short* h2 = h0 + 2*H_PL;

  if (!hasxg && tid < 16){
    int m = m0 + tid, tk;
    if (!DEC){
      tk = tok_src[m*Sv + tj];
    } else {
      if (tj == 0) tk = tok_src[m*Tv];
      else if (tf[tj] > 0) tk = tok_src[m*Tv + tj];
      else tk = (int)(~(unsigned)__hip_atomic_load(&toku[(long)(tj-1)*64 + m],
                     __ATOMIC_RELAXED, __HIP_MEMORY_SCOPE_AGENT));
    }
    stok[tid] = tk;
  }
  if (donext && tid >= 256 && tid < 272){
    stok2[tid-256] = ntok[(m0 + (tid-256))*nstride + nidx];
  }
  __syncthreads();

  if (act){
    f32x4 acc;
    if (hasxg){
      acc = *(const f32x4*)&xg[xb][g][lane][0];
    } else {
      acc = (f32x4){0.f,0.f,0.f,0.f};
      const float* e0 = emb + (long)stok[l15]*Ed;
      #pragma unroll 2
      for (int kt = 0; kt < 16; ++kt){
        const int k0 = kt*32 + lk*8;
        bf16x8 b0  = *(const bf16x8*)(w0 + ((long)kt << 9) + (lane << 3));
        bf16x8 b1v = *(const bf16x8*)(w1 + ((long)kt << 9) + (lane << 3));
        bf16x8 b2  = *(const bf16x8*)(w2 + ((long)kt << 9) + (lane << 3));
        bf16x8 a0,a1,a2;
        float4 pa = *(const float4*)(e0 + k0);
        float4 pb = *(const float4*)(e0 + k0 + 4);
        float fv[8] = {pa.x,pa.y,pa.z,pa.w,pb.x,pb.y,pb.z,pb.w};
        #pragma unroll
        for (int e=0;e<8;++e){ unsigned short s0,s1,s2; split3(fv[e],s0,s1,s2);
          a0[e]=(short)s0; a1[e]=(short)s1; a2[e]=(short)s2; }
        acc = MF(a0,b0,acc); acc = MF(a1,b0,acc); acc = MF(a0,b1v,acc);
        acc = MF(a2,b0,acc); acc = MF(a0,b2,acc); acc = MF(a1,b1v,acc);
      }
    }
    // h part: K = 512..1535 (W kt 16..47; H kt 0..31, fragment-ordered)
    #pragma unroll 2
    for (int kt = 0; kt < 32; ++kt){
      bf16x8 b0  = *(const bf16x8*)(w0 + ((long)(16+kt) << 9) + (lane << 3));
      bf16x8 b1v = *(const bf16x8*)(w1 + ((long)(16+kt) << 9) + (lane << 3));
      bf16x8 b2  = *(const bf16x8*)(w2 + ((long)(16+kt) << 9) + (lane << 3));
      const long ho = (((long)mt*32 + kt) << 9) + (lane << 3);
      bf16x8 a0 = *(const bf16x8*)(h0 + ho);
      bf16x8 a1 = *(const bf16x8*)(h1 + ho);
      bf16x8 a2 = *(const bf16x8*)(h2 + ho);
      acc = MF(a0,b0,acc); acc = MF(a1,b0,acc); acc = MF(a0,b1v,acc);
      acc = MF(a2,b0,acc); acc = MF(a0,b2,acc); acc = MF(a1,b1v,acc);
    }
    #pragma unroll
    for (int r = 0; r < 4; ++r) g4[g][lk*4 + r][l15] = acc[r];
  } else if (donext){
    xpre(lb, tid, nemb, NW0, NW1, NW2, stok2, xg[xb^1]);
  }
  __syncthreads();

  if (act){
    const int mloc = tid >> 4, cl = tid & 15;
    const int col = jh + cl;
    float ig = g4[0][mloc][cl] + bias[col];
    float fg = g4[1][mloc][cl] + bias[Hd + col];
    float gg = g4[2][mloc][cl] + bias[2*Hd + col];
    float og = g4[3][mloc][cl] + bias[3*Hd + col];
    long idx = (long)(m0 + mloc)*Hd + col;
    float cv = c[idx];
    float cn = sigf(fg)*cv + sigf(ig)*tanhf(gg);
    float hn = sigf(og)*tanhf(cn);
    c[idx] = cn;
    unsigned short s0,s1,s2; split3(hn, s0,s1,s2);
    hst[0][mloc][cl] = (short)s0; hst[1][mloc][cl] = (short)s1; hst[2][mloc][cl] = (short)s2;
  }
  __syncthreads();
  // write-once H slot_out, fragment order
  if (tid < 192){
    const int p = tid >> 6, t2 = tid & 63, r = t2 >> 2, q = t2 & 3;
    ull v =
        (ull)(unsigned short)hst[p][r][q*4]
      | ((ull)(unsigned short)hst[p][r][q*4+1] << 16)
      | ((ull)(unsigned short)hst[p][r][q*4+2] << 32)
      | ((ull)(unsigned short)hst[p][r][q*4+3] << 48);
    const int kt = (lb & 63) >> 1;
    const int off16 = (jh & 16) + q*4;
    const int lkw = off16 >> 3, keb = off16 & 7;
    ull* dst = (ull*)(H + (long)p*H_PL + (long)slot_out*65536
                      + (((long)mt*32 + kt) << 9) + ((lkw*16 + r) << 3) + keb);
    __hip_atomic_store(dst, v, __ATOMIC_RELAXED, __HIP_MEMORY_SCOPE_AGENT);
  }
}

// ---------------- argmax-only FC phase: 250 blocks x 8 waves x 16 vocab (r15-identical) ----------------
__device__ __forceinline__ void fc_phase(
    int b, int tid,
    const unsigned short* __restrict__ hhi, const unsigned short* __restrict__ hlo,
    const unsigned short* __restrict__ Wfhi, const unsigned short* __restrict__ Wflo,
    const float* __restrict__ bfc,
    ull* __restrict__ tslot, ull* amax)
{
  if (tid < 64) amax[tid] = 0ULL;
  __syncthreads();
  const int wv = tid >> 6, lane = tid & 63;
  const int l15 = lane & 15, lk = lane >> 4;
  const int vt = b*8 + wv;               // 0..1999
  const int v0 = vt*16 + l15;

  f32x4 acc[4];
  #pragma unroll
  for (int mt=0; mt<4; ++mt) acc[mt] = (f32x4){0.f,0.f,0.f,0.f};

  #pragma unroll 2
  for (int kt = 0; kt < 32; ++kt){
    const long wo = (((long)vt*32 + kt) << 9) + (lane << 3);
    bf16x8 bh = *(const bf16x8*)(Wfhi + wo);
    bf16x8 bl = *(const bf16x8*)(Wflo + wo);
    #pragma unroll
    for (int mt=0; mt<4; ++mt){
      const long ho = (((long)mt*32 + kt) << 9) + (lane << 3);
      bf16x8 ah = *(const bf16x8*)(hhi + ho);
      bf16x8 al = *(const bf16x8*)(hlo + ho);
      acc[mt] = MF(ah, bh, acc[mt]);
      acc[mt] = MF(al, bh, acc[mt]);
      acc[mt] = MF(ah, bl, acc[mt]);
    }
  }
  float bb0 = bfc[v0];
  #pragma unroll
  for (int mt=0; mt<4; ++mt){
    #pragma unroll
    for (int r=0; r<4; ++r){
      int m = mt*16 + lk*4 + r;
      float f0 = acc[mt][r] + bb0;
      unsigned u0 = __float_as_uint(f0); u0 ^= (u0 >> 31) ? 0xFFFFFFFFu : 0x80000000u;
      ull cm = ((ull)u0 << 32) | (unsigned)(~v0);
      #pragma unroll
      for (int d=1; d<16; d<<=1){
        ull o = __shfl_xor(cm, d);
        if (o > cm) cm = o;
      }
      if (l15 == 0) atomicMax(&amax[m], cm);
    }
  }
  __syncthreads();
  if (tid < 64) atomicMax(tslot + tid, amax[tid]);
}

// ---------------- the mega kernel: 256 blocks x 512 threads ----------------
__global__ __launch_bounds__(512, 1) void k_mega(
    const int* __restrict__ src, const int* __restrict__ trg, const int* __restrict__ tf,
    const float* __restrict__ enc_emb, const float* __restrict__ dec_emb,
    const float* __restrict__ b_e, const float* __restrict__ b_d,
    const float* __restrict__ bfc,
    float* __restrict__ ws)
{
  __shared__ float g4[4][16][16];
  __shared__ short hst[3][16][16];
  __shared__ int stok[16];
  __shared__ int stok2[16];
  __shared__ ull amax[64];
  __shared__ __align__(16) float xg[2][4][64][4];

  const int b = blockIdx.x, tid = threadIdx.x;
  const int lb = b;
  const int m0i = (lb >> 6) * 16;

  float* c = ws;
  unsigned short* H = (unsigned short*)(ws + OFF_H);
  const unsigned short* We0 = (const unsigned short*)(ws + OFF_WE);
  const unsigned short* We1 = We0 + W_PL;
  const unsigned short* We2 = We0 + 2*W_PL;
  const unsigned short* Wd0 = (const unsigned short*)(ws + OFF_WD);
  const unsigned short* Wd1 = Wd0 + W_PL;
  const unsigned short* Wd2 = Wd0 + 2*W_PL;
  const unsigned short* Wfhi = (const unsigned short*)(ws + OFF_WF);
  const unsigned short* Wflo = Wfhi + WF_PL;
  ull* toku = (ull*)(ws + OFF_TOK);
  int* fcnt = (int*)(ws + OFF_CNT);
  int* gcnt = fcnt + 128 + (lb >> 6)*256;
  int fbar = 0, gb = 0;

  // init: zero own c tile + stripe of H slot 64; waves 4-7 precompute xg[0] for enc t=0
  if (tid < 256){
    const int jh = (lb & 63)*16;
    const int mloc = tid >> 4, cl = tid & 15;
    c[(long)(m0i+mloc)*Hd + jh + cl] = 0.f;
    if (tid < 96){
      long off_ull = (long)lb*96 + tid;
      int p = (int)(off_ull >> 13);
      long q = off_ull & 8191;
      ull* dst = (ull*)(H + (long)p*H_PL + 64L*65536) + q;
      __hip_atomic_store(dst, 0ULL, __ATOMIC_RELAXED, __HIP_MEMORY_SCOPE_AGENT);
    }
  }
  if (tid >= 256 && tid < 272){
    stok2[tid-256] = src[(m0i + (tid-256))*Sv + 0];
  }
  __syncthreads();
  if (tid >= 256) xpre(lb, tid, enc_emb, We0, We1, We2, stok2, xg[0]);
  gbarN(fcnt, fbar++, NB);

  // encoder: slot_in = 63 + ((t+1)&1), slot_out = 63 + (t&1); t=0 reads zeroed slot 64
  for (int t = 0; t < Sv; ++t){
    const bool last = (t == Sv-1);
    lstm_phase<false>(lb, tid, 63 + ((t+1)&1), 63 + (t&1), t,
        true, t & 1,
        1, last ? trg : src, last ? Tv : Sv, last ? 0 : (t+1),
        last ? dec_emb : enc_emb,
        last ? Wd0 : We0, last ? Wd1 : We1, last ? Wd2 : We2,
        We0, We1, We2, b_e, src, (const int*)0, enc_emb, (const ull*)0,
        H, c, g4, hst, stok, stok2, xg);
    gbarN(gcnt, gb++, 64);
  }
  // decoder: step j reads slot (j==0 ? 64 : j-1), writes slot j
  for (int j = 0; j < Tv-1; ++j){
    const int step = Sv + j;
    const bool hx = (j == 0) || (tf[j] > 0);
    const int dn = (j < Tv-2 && tf[j+1] > 0) ? 1 : 0;
    lstm_phase<true>(lb, tid, (j == 0) ? 64 : (j-1), j, j,
        hx, step & 1,
        dn, trg, Tv, j+1, dec_emb, Wd0, Wd1, Wd2,
        Wd0, Wd1, Wd2, b_d, trg, tf, dec_emb, toku,
        H, c, g4, hst, stok, stok2, xg);
    if (j < Tv-2 && tf[j+1] == 0){
      gbarN(fcnt, fbar++, NB);
      if (b < 250){
        const unsigned short* h0 = H + (long)j*65536;
        fc_phase(b, tid, h0, h0 + H_PL, Wfhi, Wflo, bfc, toku + (long)j*64, amax);
      }
      gbarN(fcnt, fbar++, NB);
    } else {
      gbarN(gcnt, gb++, 64);
    }
  }
}

// ---------------- batched logits: 4 j per block, grid (500,16), fragment-ordered ----------------
__global__ __launch_bounds__(256) void k_fcall(
    const unsigned short* __restrict__ Wfhi, const unsigned short* __restrict__ Wflo,
    const float* __restrict__ bfc,
    const unsigned short* __restrict__ H, float* __restrict__ out)
{
  const int tid = threadIdx.x;
  const int wv = tid >> 6, lane = tid & 63;
  const int l15 = lane & 15, lk = lane >> 4;
  const int vt = blockIdx.x*4 + wv;
  const int vcol = vt*16 + l15;
  const int jbase = blockIdx.y*4;
  const unsigned short* h0b = H + (long)jbase*65536;
  const unsigned short* h1b = h0b + H_PL;

  f32x4 acc[4][4];
  #pragma unroll
  for (int jj=0;jj<4;++jj)
    #pragma unroll
    for (int mt=0;mt<4;++mt) acc[jj][mt] = (f32x4){0.f,0.f,0.f,0.f};

  for (int kt = 0; kt < 32; ++kt){
    const long wo = (((long)vt*32 + kt) << 9) + (lane << 3);
    bf16x8 bh = *(const bf16x8*)(Wfhi + wo);
    bf16x8 bl = *(const bf16x8*)(Wflo + wo);
    #pragma unroll
    for (int jj=0;jj<4;++jj){
      if (jbase + jj <= 62){
        #pragma unroll
        for (int mt=0;mt<4;++mt){
          const long ho = (long)jj*65536 + (((long)mt*32 + kt) << 9) + (lane << 3);
          bf16x8 ah = *(const bf16x8*)(h0b + ho);
          bf16x8 al = *(const bf16x8*)(h1b + ho);
          acc[jj][mt] = MF(ah, bh, acc[jj][mt]);
          acc[jj][mt] = MF(al, bh, acc[jj][mt]);
          acc[jj][mt] = MF(ah, bl, acc[jj][mt]);
        }
      }
    }
  }
  float bb = bfc[vcol];
  #pragma unroll
  for (int jj=0;jj<4;++jj){
    if (jbase + jj <= 62){
      #pragma unroll
      for (int mt=0;mt<4;++mt){
        #pragma unroll
        for (int r=0;r<4;++r){
          int m = mt*16 + lk*4 + r;
          out[((long)m*Tv + (jbase+jj+1))*(long)Vv + vcol] = acc[jj][mt][r] + bb;
        }
      }
    }
  }
  if (blockIdx.y == 0){
    const int vb = blockIdx.x*64;
    for (int i = tid; i < 4096; i += 256){
      int m = i >> 6, v = vb + (i & 63);
      out[(long)m*Tv*(long)Vv + v] = 0.f;
    }
  }
}

// ---------------- fallback (round-2 proven path, used only if ws too small) ----------------

__global__ __launch_bounds__(256) void k_initC(float* __restrict__ ws, float* __restrict__ out){
  long i = (long)blockIdx.x*256 + threadIdx.x;
  if (i < 262144){ ws[i] = 0.f; }
  else {
    long r = i - 262144;
    long m = r / Vv, v = r % Vv;
    out[m*Tv*(long)Vv + v] = 0.f;
  }
}

__global__ __launch_bounds__(256) void k_stepC(
    int mode, int t,
    const int* __restrict__ tok_src, const int* __restrict__ tf_mask,
    const int* __restrict__ token_buf, const float* __restrict__ emb,
    const float* __restrict__ Wih, const float* __restrict__ Whh,
    const float* __restrict__ bias,
    const float* __restrict__ h_in, const float* __restrict__ c_in,
    float* __restrict__ h_out, float* __restrict__ c_out,
    unsigned short* __restrict__ hsp_hi, unsigned short* __restrict__ hsp_lo)
{
  __shared__ __align__(16) float tile[8*1536];
  __shared__ float gbuf[4*8*32];
  __shared__ int toks[8];
  const int tid = threadIdx.x;
  const int m0 = blockIdx.y*8, jh0 = blockIdx.x*32;
  if (tid < 8){
    int m = m0 + tid; int tok;
    if (mode == 0) tok = tok_src[m*Sv + t];
    else { if (t == 0) tok = tok_src[m*Tv];
           else tok = (tf_mask[t] > 0) ? tok_src[m*Tv + t] : token_buf[m]; }
    toks[tid] = tok;
  }
  __syncthreads();
  { float4* t4 = (float4*)tile;
    #pragma unroll
    for (int r = 0; r < 12; ++r){
      int f = tid + 256*r; int row = f / 384, o = f % 384; float4 v;
      if (o < 128) v = ((const float4*)(emb + (long)toks[row]*Ed))[o];
      else         v = ((const float4*)(h_in + (long)(m0+row)*Hd))[o-128];
      t4[row*384 + o] = v; } }
  __syncthreads();
  const int g = tid >> 6, sx = tid & 63, jl = sx & 31, mg = sx >> 5;
  const int col = g*Hd + jh0 + jl;
  const float4* wx = (const float4*)(Wih + (long)col*Ed);
  const float4* wh = (const float4*)(Whh + (long)col*Hd);
  const float4* t4 = (const float4*)tile;
  const int mb = mg*4;
  float bq = bias[col];
  float a0=bq, a1=bq, a2=bq, a3=bq;
  for (int k = 0; k < 128; ++k){
    float4 w = wx[k];
    float4 v0 = t4[(mb+0)*384 + k]; float4 v1 = t4[(mb+1)*384 + k];
    float4 v2 = t4[(mb+2)*384 + k]; float4 v3 = t4[(mb+3)*384 + k];
    a0 += w.x*v0.x + w.y*v0.y + w.z*v0.z + w.w*v0.w;
    a1 += w.x*v1.x + w.y*v1.y + w.z*v1.z + w.w*v1.w;
    a2 += w.x*v2.x + w.y*v2.y + w.z*v2.z + w.w*v2.w;
    a3 += w.x*v3.x + w.y*v3.y + w.z*v3.z + w.w*v3.w;
  }
  for (int k = 0; k < 256; ++k){
    float4 w = wh[k];
    float4 v0 = t4[(mb+0)*384 + 128 + k]; float4 v1 = t4[(mb+1)*384 + 128 + k];
    float4 v2 = t4[(mb+2)*384 + 128 + k]; float4 v3 = t4[(mb+3)*384 + 128 + k];
    a0 += w.x*v0.x + w.y*v0.y + w.z*v0.z + w.w*v0.w;
    a1 += w.x*v1.x + w.y*v1.y + w.z*v1.z + w.w*v1.w;
    a2 += w.x*v2.x + w.y*v2.y + w.z*v2.z + w.w*v2.w;
    a3 += w.x*v3.x + w.y*v3.y + w.z*v3.z + w.w*v3.w;
  }
  gbuf[g*256 + (mb+0)*32 + jl] = a0; gbuf[g*256 + (mb+1)*32 + jl] = a1;
  gbuf[g*256 + (mb+2)*32 + jl] = a2; gbuf[g*256 + (mb+3)*32 + jl] = a3;
  __syncthreads();
  const int ml = tid >> 5, j2 = tid & 31;
  float ig = gbuf[0*256 + ml*32 + j2];
  float fg = gbuf[1*256 + ml*32 + j2];
  float gg = gbuf[2*256 + ml*32 + j2];
  float og = gbuf[3*256 + ml*32 + j2];
  long idx = (long)(m0+ml)*Hd + jh0 + j2;
  float cc = c_in[idx];
  float cn = sigf(fg)*cc + sigf(ig)*tanhf(gg);
  float hn = sigf(og)*tanhf(cn);
  c_out[idx] = cn; h_out[idx] = hn;
  unsigned short hh = f2bf(hn);
  hsp_hi[idx] = hh; hsp_lo[idx] = f2bf(hn - bf2f(hh));
}

__global__ __launch_bounds__(256) void k_fcC(
    int j, const unsigned short* __restrict__ hhi, const unsigned short* __restrict__ hlo,
    const float* __restrict__ Wfc, const float* __restrict__ bfc, float* __restrict__ out)
{
  const int tid = threadIdx.x;
  const int wv = tid >> 6, lane = tid & 63;
  const int l15 = lane & 15, lk = lane >> 4;
  const int vcol = blockIdx.x*64 + wv*16 + l15;
  const float* wrow = Wfc + (long)vcol*Hd;
  f32x4 acc[4];
  #pragma unroll
  for (int mt=0; mt<4; ++mt) acc[mt] = (f32x4){0.f,0.f,0.f,0.f};
  #pragma unroll 2
  for (int kt = 0; kt < 32; ++kt){
    const int k0 = kt*32 + lk*8;
    float4 wa = *(const float4*)(wrow + k0);
    float4 wb = *(const float4*)(wrow + k0 + 4);
    float wf[8] = {wa.x,wa.y,wa.z,wa.w,wb.x,wb.y,wb.z,wb.w};
    bf16x8 bh, bl;
    #pragma unroll
    for (int e=0;e<8;++e){
      unsigned short h = f2bf(wf[e]);
      bh[e] = (short)h; bl[e] = (short)f2bf(wf[e] - bf2f(h));
    }
    #pragma unroll
    for (int mt=0; mt<4; ++mt){
      const int row = mt*16 + l15;
      bf16x8 ah = *(const bf16x8*)(hhi + row*Hd + k0);
      bf16x8 al = *(const bf16x8*)(hlo + row*Hd + k0);
      acc[mt] = MF(ah, bh, acc[mt]);
      acc[mt] = MF(al, bh, acc[mt]);
      acc[mt] = MF(ah, bl, acc[mt]);
    }
  }
  float bb = bfc[vcol];
  #pragma unroll
  for (int mt=0; mt<4; ++mt)
    #pragma unroll
    for (int r=0; r<4; ++r){
      int m = mt*16 + lk*4 + r;
      out[((long)m*Tv + (j+1))*(long)Vv + vcol] = acc[mt][r] + bb;
    }
}

__global__ __launch_bounds__(256) void k_argmaxC(
    int j, const float* __restrict__ out, int* __restrict__ token_buf)
{
  __shared__ float sval[256];
  __shared__ int   sidx[256];
  const int m = blockIdx.x, tid = threadIdx.x;
  const float* base = out + ((long)m*Tv + (j+1))*(long)Vv;
  float best = -INFINITY; int bi = 0;
  for (int v = tid; v < Vv; v += 256){
    float f = base[v];
    if (f > best){ best = f; bi = v; }
  }
  sval[tid] = best; sidx[tid] = bi;
  __syncthreads();
  for (int s2 = 128; s2 > 0; s2 >>= 1){
    if (tid < s2){
      float ov = sval[tid+s2]; int oi = sidx[tid+s2];
      if (ov > sval[tid] || (ov == sval[tid] && oi < sidx[tid])){
        sval[tid] = ov; sidx[tid] = oi;
      }
    }
    __syncthreads();
  }
  if (tid == 0) token_buf[m] = sidx[0];
}

extern "C" void kernel_launch(void* const* d_in, const int* in_sizes, int n_in,
                              void* d_out, int out_size, void* d_ws, size_t ws_size,
                              hipStream_t stream)
{
  const int*   src     = (const int*)  d_in[0];
  const int*   trg     = (const int*)  d_in[1];
  const int*   tf      = (const int*)  d_in[2];
  const float* enc_emb = (const float*)d_in[3];
  const float* dec_emb = (const float*)d_in[4];
  const float* Wih_e   = (const float*)d_in[5];
  const float* Whh_e   = (const float*)d_in[6];
  const float* b_e     = (const float*)d_in[7];
  const float* Wih_d   = (const float*)d_in[8];
  const float* Whh_d   = (const float*)d_in[9];
  const float* b_d     = (const float*)d_in[10];
  const float* Wfc     = (const float*)d_in[11];
  const float* bfc     = (const float*)d_in[12];
  float* out = (float*)d_out;
  float* ws  = (float*)d_ws;

  if (ws_size >= (size_t)NEED_FL * 4ULL){
    unsigned short* We0 = (unsigned short*)(ws + OFF_WE);
    unsigned short* Wd0 = (unsigned short*)(ws + OFF_WD);
    unsigned short* Wf0 = (unsigned short*)(ws + OFF_WF);
    unsigned short* Hb  = (unsigned short*)(ws + OFF_H);

    hipMemsetAsync((void*)(ws + OFF_TOK), 0, (size_t)(NEED_FL - OFF_TOK) * 4ULL, stream);
    k_wsplit3<<<4096, 256, 0, stream>>>(Wih_e, Whh_e, We0, We0 + W_PL, We0 + 2*W_PL);
    k_wsplit3<<<4096, 256, 0, stream>>>(Wih_d, Whh_d, Wd0, Wd0 + W_PL, Wd0 + 2*W_PL);
    k_wfsplit<<<32000, 256, 0, stream>>>(Wfc, Wf0, Wf0 + WF_PL);
    k_mega<<<NB, 512, 0, stream>>>(src, trg, tf, enc_emb, dec_emb, b_e, b_d, bfc, ws);
    k_fcall<<<dim3(500, 16), 256, 0, stream>>>(Wf0, Wf0 + WF_PL, bfc, Hb, out);
  } else {
    // fallback: round-2 proven multi-kernel path
    float* hbuf[2] = { ws,            ws + 65536 };
    float* cbuf[2] = { ws + 131072,   ws + 196608 };
    int*   tokbuf  = (int*)(ws + 262144);
    unsigned short* hsp_hi = (unsigned short*)(ws + 262208);
    unsigned short* hsp_lo = (unsigned short*)(ws + 262208 + 32768);

    k_initC<<<9024, 256, 0, stream>>>(ws, out);
    int cur = 0;
    for (int t = 0; t < Sv; ++t){
      k_stepC<<<dim3(32,8), 256, 0, stream>>>(0, t, src, tf, tokbuf, enc_emb,
          Wih_e, Whh_e, b_e, hbuf[cur], cbuf[cur], hbuf[cur^1], cbuf[cur^1], hsp_hi, hsp_lo);
      cur ^= 1;
    }
    for (int j = 0; j < Tv-1; ++j){
      k_stepC<<<dim3(32,8), 256, 0, stream>>>(1, j, trg, tf, tokbuf, dec_emb,
          Wih_d, Whh_d, b_d, hbuf[cur], cbuf[cur], hbuf[cur^1], cbuf[cur^1], hsp_hi, hsp_lo);
      cur ^= 1;
      k_fcC<<<500, 256, 0, stream>>>(j, hsp_hi, hsp_lo, Wfc, bfc, out);
      if (j < Tv-2) k_argmaxC<<<64, 256, 0, stream>>>(j, out, tokbuf);
    }
  }
}